// Round 11
// baseline (206.337 us; speedup 1.0000x reference)
//
#include <hip/hip_runtime.h>
#include <math.h>

#define HH 256
#define WW 256
#define NPIX 65536
#define BATCH 2

// ---------------- workspace layout (floats) ----------------
#define OFF_W0   0u                 // A16 bf16 / G32 bf16 / G64 bf16
#define OFF_W1   8388608u           // H32/H64 bf16, then FF bf16
#define OFF_W2   16777216u          // AT1 bf16 swizzled; later ENH bf16 [ch][px]
#define OFF_W3   20971520u          // AT2 bf16 swizzled
#define OFF_S    25165824u
#define OFF_D    25296896u
#define OFF_STAT 25427968u
#define OFF_ST1  (OFF_STAT + 0u)
#define OFF_ST2  (OFF_STAT + 64u)
#define OFF_ST3  (OFF_STAT + 192u)
#define OFF_ST4  (OFF_STAT + 448u)
#define STAT_ZERO_N 704
#define OFF_WB1  (OFF_STAT + 704u)            // bf16 [9][32][64] = 18432 u16
#define OFF_WB2  (OFF_WB1 + 18432u)           // bf16 [9][64][32] = 18432 u16

typedef __attribute__((ext_vector_type(8))) short bf8v;            // 8 bf16 = 16 B
typedef __attribute__((ext_vector_type(4))) float f4v;
typedef __attribute__((ext_vector_type(4))) unsigned short us4;    // 4 bf16 = 8 B

#define GLL16(g, l) __builtin_amdgcn_global_load_lds(                               \
    (const __attribute__((address_space(1))) unsigned int*)(g),                    \
    (__attribute__((address_space(3))) unsigned int*)(l), 16, 0, 0)

// ---------------- helpers ----------------
__device__ __forceinline__ unsigned short f2bf(float f) {
    unsigned u = __float_as_uint(f);
    return (unsigned short)((u + 0x7FFFu + ((u >> 16) & 1u)) >> 16);
}
__device__ __forceinline__ float bf2f(unsigned short u) {
    return __uint_as_float(((unsigned)u) << 16);
}

__device__ __forceinline__ void bn_coef(const float* __restrict__ raw,
                                        const float* __restrict__ g,
                                        const float* __restrict__ b,
                                        int C, int c, float& A, float& Bv) {
    const float inv = 1.f / (float)(BATCH * NPIX);
    float mu  = raw[c] * inv;
    float var = raw[C + c] * inv - mu * mu;
    float rinv = rsqrtf(var + 1e-5f);
    A  = g[c] * rinv;
    Bv = b[c] - A * mu;
}

__device__ __forceinline__ void wave_red2(float& s, float& q) {
#pragma unroll
    for (int off = 32; off; off >>= 1) {
        s += __shfl_xor(s, off);
        q += __shfl_xor(q, off);
    }
}

// ---------------- fused prep: zero stats + both weight repacks ----------------
__global__ void prep(float* __restrict__ st,
                     const float* __restrict__ w1, unsigned short* __restrict__ wb1,
                     const float* __restrict__ w2, unsigned short* __restrict__ wb2) {
    int bid = blockIdx.x, tid = threadIdx.x;
    if (bid < 3) {
        int i = bid * 256 + tid;
        if (i < STAT_ZERO_N) st[i] = 0.f;
    } else if (bid < 75) {
        int i = (bid - 3) * 256 + tid;       // CO=32, CI=64
        int co = i / (64 * 9);
        int rem = i - co * 64 * 9;
        int ci = rem / 9;
        int pos = rem - ci * 9;
        wb1[(pos * 32 + co) * 64 + ci] = f2bf(w1[i]);
    } else {
        int i = (bid - 75) * 256 + tid;      // CO=64, CI=32
        int co = i / (32 * 9);
        int rem = i - co * 32 * 9;
        int ci = rem / 9;
        int pos = rem - ci * 9;
        wb2[(pos * 64 + co) * 32 + ci] = f2bf(w2[i]);
    }
}

// ---------------- conv1 5x5, 1->16, relu, bf16 out, fused bn1 stats ----------------
__global__ __launch_bounds__(256) void conv5x5_all(const float* __restrict__ x,
                                                   const float* __restrict__ w,
                                                   const float* __restrict__ bias,
                                                   unsigned short* __restrict__ out,
                                                   float* __restrict__ st) {
    int y = blockIdx.x, b = blockIdx.y;
    int xx = threadIdx.x;
    __shared__ float lds[5 * 260];
    __shared__ float red[2][16][4];
    for (int i = threadIdx.x; i < 5 * 260; i += 256) {
        int r = i / 260, pos = i - r * 260;
        int yy = y + r - 2, xc = pos - 2;
        float v = 0.f;
        if ((unsigned)yy < 256u && (unsigned)xc < 256u) v = x[(b << 16) + (yy << 8) + xc];
        lds[i] = v;
    }
    __syncthreads();
    float v[25];
#pragma unroll
    for (int r = 0; r < 5; r++)
#pragma unroll
        for (int c = 0; c < 5; c++) v[r * 5 + c] = lds[r * 260 + xx + c];
    int lane = threadIdx.x & 63, wv = threadIdx.x >> 6;
#pragma unroll
    for (int co = 0; co < 16; co++) {
        float acc = bias[co];
#pragma unroll
        for (int k = 0; k < 25; k++) acc = fmaf(v[k], w[co * 25 + k], acc);
        acc = fmaxf(acc, 0.f);
        out[((size_t)(b * 16 + co) << 16) + (y << 8) + xx] = f2bf(acc);
        float s = acc, q = acc * acc;
        wave_red2(s, q);
        if (lane == 0) { red[0][co][wv] = s; red[1][co][wv] = q; }
    }
    __syncthreads();
    if (threadIdx.x < 16) {
        int co = threadIdx.x;
        float s = red[0][co][0] + red[0][co][1] + red[0][co][2] + red[0][co][3];
        float q = red[1][co][0] + red[1][co][1] + red[1][co][2] + red[1][co][3];
        atomicAdd(&st[co], s);
        atomicAdd(&st[16 + co], q);
    }
}

// ---------------- GAT pre: bn + pos + h GEMM (bf16 in/out) + s/d ----------------
template <int CI, int CO>
__global__ __launch_bounds__(256) void gat_pre(const unsigned short* __restrict__ f,
                        const float* __restrict__ raw,
                        const float* __restrict__ bng, const float* __restrict__ bnb,
                        const float* __restrict__ posw, const float* __restrict__ posb,
                        const float* __restrict__ gw, const float* __restrict__ gas,
                        const float* __restrict__ gad,
                        unsigned short* __restrict__ hout, float* __restrict__ sout,
                        float* __restrict__ dout) {
    __shared__ float Ash[CI], Bsh[CI];
    if (threadIdx.x < CI) {
        float A, Bv;
        bn_coef(raw, bng, bnb, CI, threadIdx.x, A, Bv);
        Ash[threadIdx.x] = A;
        Bsh[threadIdx.x] = Bv + posb[threadIdx.x];
    }
    __syncthreads();
    int tid = blockIdx.x * 256 + threadIdx.x;
    int n = tid & (NPIX - 1);
    int b = tid >> 16;
    int y = n >> 8, x = n & 255;
    float py = y * (2.f / 255.f) - 1.f;
    float px = x * (2.f / 255.f) - 1.f;
    float v[CI];
#pragma unroll
    for (int ci = 0; ci < CI; ci++) {
        float t = fmaf(bf2f(f[(size_t)(b * CI + ci) * NPIX + n]), Ash[ci], Bsh[ci]);
        v[ci] = t + posw[2 * ci] * py + posw[2 * ci + 1] * px;
    }
    float s = 0.f, d = 0.f;
    for (int co = 0; co < CO; co++) {
        float acc = 0.f;
#pragma unroll
        for (int ci = 0; ci < CI; ci++) acc = fmaf(v[ci], gw[co * CI + ci], acc);
        hout[(size_t)(b * CO + co) * NPIX + n] = f2bf(acc);
        s = fmaf(acc, gas[co], s);
        d = fmaf(acc, gad[co], d);
    }
    sout[tid] = s;
    dout[tid] = d;
}

// ---------------- GAT stencil via MFMA, phase-split + CO-split ----------------
template <int CO, bool POOL>
__global__ __launch_bounds__(256) void gat_stencil_mfma(const unsigned short* __restrict__ hb,
                                                        const float* __restrict__ sbuf,
                                                        const float* __restrict__ dbuf,
                                                        const float* __restrict__ gb,
                                                        unsigned short* __restrict__ out,
                                                        float* __restrict__ st) {
    constexpr int NT2 = CO / 32;           // 16-ch tiles per wave (co-half)
    constexpr int CH = CO / 2;             // channels per half
    int bid = blockIdx.x;                  // 1024
    int orig = (bid & 7) * 128 + (bid >> 3);
    int coh = orig & 1;
    int rowu = orig >> 1;                  // [0,512)
    int y = rowu & 255;
    int b = rowu >> 8;
    int tid = threadIdx.x, lane = tid & 63, wid = tid >> 6;
    int m = lane & 15, grp = lane >> 4;
    int xw = wid * 64;                     // wave's 64-px span
    // ---- phase 1: per-pixel softmax ----
    int x = xw + lane;
    float di = dbuf[(b << 16) + (y << 8) + x];
    float p[9], mx = -1e30f;
#pragma unroll
    for (int k = 0; k < 9; k++) {
        int dy = k / 3 - 1, dx = k % 3 - 1;
        int yy = y + dy, xxn = x + dx;
        bool ok = ((unsigned)yy < 256u) && ((unsigned)xxn < 256u);
        float e = -1e30f;
        if (ok) {
            float t = sbuf[(b << 16) + (yy << 8) + xxn] + di;
            e = t > 0.f ? t : 0.2f * t;
        }
        p[k] = e;
        mx = fmaxf(mx, e);
    }
    float den = 0.f;
#pragma unroll
    for (int k = 0; k < 9; k++) { p[k] = __expf(p[k] - mx); den += p[k]; }
    float rden = 1.f / (den + 1e-16f);
    unsigned short pb[9];
#pragma unroll
    for (int k = 0; k < 9; k++) pb[k] = f2bf(p[k] * rden);
    unsigned pk0 = (unsigned)pb[0] | ((unsigned)pb[1] << 16);
    unsigned pk1 = (unsigned)pb[2] | ((unsigned)pb[3] << 16);
    unsigned pk2 = (unsigned)pb[4] | ((unsigned)pb[5] << 16);
    unsigned pk3 = (unsigned)pb[6] | ((unsigned)pb[7] << 16);
    unsigned pk4 = (unsigned)pb[8];
    float sAcc[NT2], qAcc[NT2], bb[NT2];
#pragma unroll
    for (int ct = 0; ct < NT2; ct++) {
        sAcc[ct] = 0.f; qAcc[ct] = 0.f;
        bb[ct] = gb[coh * CH + ct * 16 + m];
    }
    // ---- phase 2: 4 tiles ----
#pragma unroll 1
    for (int t = 0; t < 4; t++) {
        int xb = xw + t * 16;
        int src = t * 16 + m;
        unsigned rk0 = __shfl(pk0, src);
        unsigned rk1 = __shfl(pk1, src);
        unsigned rk2 = __shfl(pk2, src);
        unsigned rk3 = __shfl(pk3, src);
        unsigned rk4 = __shfl(pk4, src);
        unsigned short rb[9];
        rb[0] = (unsigned short)rk0; rb[1] = (unsigned short)(rk0 >> 16);
        rb[2] = (unsigned short)rk1; rb[3] = (unsigned short)(rk1 >> 16);
        rb[4] = (unsigned short)rk2; rb[5] = (unsigned short)(rk2 >> 16);
        rb[6] = (unsigned short)rk3; rb[7] = (unsigned short)(rk3 >> 16);
        rb[8] = (unsigned short)rk4;
        union { bf8v v; unsigned short h[8]; } af[3];
#pragma unroll
        for (int dyi = 0; dyi < 3; dyi++)
#pragma unroll
            for (int j = 0; j < 8; j++) {
                int k = grp * 8 + j;
                int d = k - 8 - m;
                af[dyi].h[j] = (d >= -1 && d <= 1) ? rb[dyi * 3 + d + 1] : (unsigned short)0;
            }
        f4v acc[NT2];
        f4v z4 = {0.f, 0.f, 0.f, 0.f};
#pragma unroll
        for (int ct = 0; ct < NT2; ct++) acc[ct] = z4;
        int px0 = xb - 8 + grp * 8;
        px0 = px0 < 0 ? 0 : (px0 > 248 ? 248 : px0);
#pragma unroll
        for (int dyi = 0; dyi < 3; dyi++) {
            int yy = y + dyi - 1;
            if ((unsigned)yy >= 256u) continue;
#pragma unroll
            for (int ct = 0; ct < NT2; ct++) {
                int ch = coh * CH + ct * 16 + m;
                bf8v bv = *(const bf8v*)(hb + (((size_t)(b * CO + ch)) << 16) + (yy << 8) + px0);
                acc[ct] = __builtin_amdgcn_mfma_f32_16x16x32_bf16(af[dyi].v, bv, acc[ct], 0, 0, 0);
            }
        }
        int pxr = xb + grp * 4;
#pragma unroll
        for (int ct = 0; ct < NT2; ct++) {
            int ch = coh * CH + ct * 16 + m;
            f4v a = acc[ct];
            float o0 = fmaxf(a[0] + bb[ct], 0.f);
            float o1 = fmaxf(a[1] + bb[ct], 0.f);
            float o2 = fmaxf(a[2] + bb[ct], 0.f);
            float o3 = fmaxf(a[3] + bb[ct], 0.f);
            us4 pkst = {f2bf(o0), f2bf(o1), f2bf(o2), f2bf(o3)};
            *(us4*)(out + (((size_t)(b * CO + ch)) << 16) + (y << 8) + pxr) = pkst;
            sAcc[ct] += o0 + o1 + o2 + o3;
            qAcc[ct] += o0 * o0 + o1 * o1 + o2 * o2 + o3 * o3;
        }
    }
    // ---- stats ----
#pragma unroll
    for (int ct = 0; ct < NT2; ct++) {
        sAcc[ct] += __shfl_xor(sAcc[ct], 16); sAcc[ct] += __shfl_xor(sAcc[ct], 32);
        qAcc[ct] += __shfl_xor(qAcc[ct], 16); qAcc[ct] += __shfl_xor(qAcc[ct], 32);
    }
    __shared__ float red[2][NT2][16][4];
    if (grp == 0) {
#pragma unroll
        for (int ct = 0; ct < NT2; ct++) {
            red[0][ct][m][wid] = sAcc[ct];
            red[1][ct][m][wid] = qAcc[ct];
        }
    }
    __syncthreads();
    if (tid < CH) {
        int ct = tid >> 4, mm = tid & 15;
        int c = coh * CH + tid;
        float s = red[0][ct][mm][0] + red[0][ct][mm][1] + red[0][ct][mm][2] + red[0][ct][mm][3];
        float qq = red[1][ct][mm][0] + red[1][ct][mm][1] + red[1][ct][mm][2] + red[1][ct][mm][3];
        atomicAdd(&st[c], s);
        atomicAdd(&st[CO + c], qq);
        if (POOL) atomicAdd(&st[2 * CO + b * CO + c], s);
    }
}

// ---------------- ff (bf16 out) + transpose + FUSED channel-weight MLP ----------------
__global__ __launch_bounds__(256) void ff_t(const unsigned short* __restrict__ g64,
                                            const float* __restrict__ raw3,
                                            const float* __restrict__ g3,
                                            const float* __restrict__ b3,
                                            const float* __restrict__ w1,
                                            const float* __restrict__ bb1,
                                            const float* __restrict__ w2,
                                            const float* __restrict__ bb2,
                                            const float* __restrict__ filt,
                                            const float* __restrict__ fbias,
                                            unsigned short* __restrict__ ffout,
                                            unsigned* __restrict__ at1) {
    __shared__ float pooled[2][64];
    __shared__ float hsh[2][16];
    __shared__ float cwsh[2][64];
    __shared__ unsigned t[64 * 33];
    int tid = threadIdx.x;
    if (tid < 128) {
        int b = tid >> 6, c = tid & 63;
        float A, Bv;
        bn_coef(raw3, g3, b3, 64, c, A, Bv);
        float sm = raw3[128 + (b << 6) + c];
        pooled[b][c] = fmaf(sm * (1.f / 65536.f), A, Bv);
    }
    __syncthreads();
    if (tid < 32) {
        int b = tid >> 4, j = tid & 15;
        float acc = bb1[j];
        for (int c2 = 0; c2 < 64; c2++) acc = fmaf(pooled[b][c2], w1[(j << 6) + c2], acc);
        hsh[b][j] = fmaxf(acc, 0.f);
    }
    __syncthreads();
    if (tid < 128) {
        int b = tid >> 6, c = tid & 63;
        float logit = bb2[c];
        for (int j = 0; j < 16; j++) logit = fmaf(hsh[b][j], w2[(c << 4) + j], logit);
        float mm = logit;
#pragma unroll
        for (int off = 32; off; off >>= 1) mm = fmaxf(mm, __shfl_xor(mm, off));
        float e = __expf(logit - mm);
        float ss = e;
#pragma unroll
        for (int off = 32; off; off >>= 1) ss += __shfl_xor(ss, off);
        cwsh[b][c] = e / ss;
    }
    __syncthreads();
    int pxb = blockIdx.x * 64;
    int b = pxb >> 16;
    int nb = pxb & 65535;
#pragma unroll
    for (int k = 0; k < 2; k++) {
        int u = tid + k * 256;
        int q = u & 15;
        int cp = u >> 4;
        int ch0 = cp * 2, ch1 = ch0 + 1;
        float A0, B0, A1, B1;
        bn_coef(raw3, g3, b3, 64, ch0, A0, B0);
        bn_coef(raw3, g3, b3, 64, ch1, A1, B1);
        float s0 = cwsh[b][ch0], s1 = cwsh[b][ch1];
        float fb0 = fbias[ch0], fb1 = fbias[ch1];
        int n = nb + q * 4;
        us4 r0 = *(const us4*)(g64 + ((size_t)(b * 64 + ch0) << 16) + n);
        us4 r1 = *(const us4*)(g64 + ((size_t)(b * 64 + ch1) << 16) + n);
        float4 l0 = *(const float4*)(filt + ((size_t)ch0 << 16) + n);
        float4 l1 = *(const float4*)(filt + ((size_t)ch1 << 16) + n);
        float4 o0, o1;
        o0.x = fmaf(fmaf(bf2f(r0[0]), A0, B0) * s0, l0.x, fb0);
        o0.y = fmaf(fmaf(bf2f(r0[1]), A0, B0) * s0, l0.y, fb0);
        o0.z = fmaf(fmaf(bf2f(r0[2]), A0, B0) * s0, l0.z, fb0);
        o0.w = fmaf(fmaf(bf2f(r0[3]), A0, B0) * s0, l0.w, fb0);
        o1.x = fmaf(fmaf(bf2f(r1[0]), A1, B1) * s1, l1.x, fb1);
        o1.y = fmaf(fmaf(bf2f(r1[1]), A1, B1) * s1, l1.y, fb1);
        o1.z = fmaf(fmaf(bf2f(r1[2]), A1, B1) * s1, l1.z, fb1);
        o1.w = fmaf(fmaf(bf2f(r1[3]), A1, B1) * s1, l1.w, fb1);
        us4 f0 = {f2bf(o0.x), f2bf(o0.y), f2bf(o0.z), f2bf(o0.w)};
        us4 f1 = {f2bf(o1.x), f2bf(o1.y), f2bf(o1.z), f2bf(o1.w)};
        *(us4*)(ffout + ((size_t)(b * 64 + ch0) << 16) + n) = f0;
        *(us4*)(ffout + ((size_t)(b * 64 + ch1) << 16) + n) = f1;
#pragma unroll
        for (int i = 0; i < 4; i++)
            t[(q * 4 + i) * 33 + cp] = (unsigned)f0[i] | ((unsigned)f1[i] << 16);
    }
    __syncthreads();
#pragma unroll
    for (int j = 0; j < 8; j++) {
        int lin = j * 256 + tid;
        int pl = lin >> 5, cp = lin & 31;
        unsigned v = t[pl * 33 + cp];
        int P = pxb + pl;
        size_t byte = ((size_t)P << 7) + ((cp >= 16) ? 64 : 0)
                    + (((cp & 15) * 4) ^ (((P >> 1) & 3) << 4));
        *(unsigned*)((char*)at1 + byte) = v;
    }
}

// ---------------- enh1: 3x3 conv 64->32 via MFMA (half-row blocks), relu, bf16 out ----------------
// 1024 blocks XCD-swizzled; LDS [3 rows][160 slots][32 ch-half], slot s -> px = xb-16+s.
__global__ __launch_bounds__(256) void enh1_mfma(const unsigned short* __restrict__ at1,
                                                 const unsigned short* __restrict__ wb,  // [9][32][64]
                                                 const float* __restrict__ bias,
                                                 unsigned short* __restrict__ at2) {
    int bid = blockIdx.x;                  // 1024
    int orig = (bid & 7) * 128 + (bid >> 3);
    int hlf = orig & 1;
    int rowu = orig >> 1;
    int y = rowu & 255, b = rowu >> 8;
    int xb = hlf * 128;
    int tid = threadIdx.x;
    int lane = tid & 63, wid = tid >> 6;
    __shared__ __align__(16) unsigned short lds_u16[3 * 160 * 32];
    char* ldsb = (char*)lds_u16;
    {
        bf8v z = {0, 0, 0, 0, 0, 0, 0, 0};
        for (int i = tid; i < 3 * 160 * 32 / 8; i += 256) ((bf8v*)lds_u16)[i] = z;
    }
    f4v acc[2][2];
    {
        f4v z4 = {0.f, 0.f, 0.f, 0.f};
#pragma unroll
        for (int m = 0; m < 2; m++) { acc[m][0] = z4; acc[m][1] = z4; }
    }
#pragma unroll 1
    for (int kh = 0; kh < 2; kh++) {
        __syncthreads();
        // stage: 3 rows x 10 chunks (16 px x 64B), px chunk base = xb-16+16k
        for (int c = wid; c < 30; c += 4) {
            int r = c / 10, k = c - r * 10;
            int yy = y + r - 1;
            int pxc = xb - 16 + k * 16;
            if ((unsigned)yy < 256u && (unsigned)pxc < 256u) {
                const char* src = (const char*)at1
                    + (((size_t)((b << 16) + (yy << 8)) + (pxc + (lane >> 2))) << 7)
                    + kh * 64 + (lane & 3) * 16;
                char* dst = ldsb + r * 10240 + k * 1024;
                GLL16(src, dst);
            }
        }
        __syncthreads();
        bf8v bw0[9], bw1[9];
#pragma unroll
        for (int pos = 0; pos < 9; pos++) {
            bw0[pos] = *(const bf8v*)(wb + (pos * 32 + (lane & 15)) * 64 + kh * 32 + (lane >> 4) * 8);
            bw1[pos] = *(const bf8v*)(wb + (pos * 32 + 16 + (lane & 15)) * 64 + kh * 32 + (lane >> 4) * 8);
        }
#pragma unroll
        for (int mt = 0; mt < 2; mt++) {
            int xg = xb + (wid * 2 + mt) * 16 + (lane & 15);
#pragma unroll
            for (int ky = 0; ky < 3; ky++) {
#pragma unroll
                for (int kx = 0; kx < 3; kx++) {
                    int x = xg + kx - 1;
                    int sl = x - xb + 16;
                    int off = (ky * 160 + sl) * 64 + (((lane >> 4) * 16) ^ (((x >> 1) & 3) << 4));
                    bf8v a = *(const bf8v*)(ldsb + off);
                    acc[mt][0] = __builtin_amdgcn_mfma_f32_16x16x32_bf16(a, bw0[ky * 3 + kx], acc[mt][0], 0, 0, 0);
                    acc[mt][1] = __builtin_amdgcn_mfma_f32_16x16x32_bf16(a, bw1[ky * 3 + kx], acc[mt][1], 0, 0, 0);
                }
            }
        }
    }
    float bb[2] = {bias[lane & 15], bias[16 + (lane & 15)]};
#pragma unroll
    for (int mt = 0; mt < 2; mt++) {
#pragma unroll
        for (int nt = 0; nt < 2; nt++) {
            f4v v = acc[mt][nt];
            int co = nt * 16 + (lane & 15);
#pragma unroll
            for (int r = 0; r < 4; r++) {
                int x = xb + (wid * 2 + mt) * 16 + (lane >> 4) * 4 + r;
                float val = fmaxf(v[r] + bb[nt], 0.f);
                size_t byte = (((size_t)((b << 16) + (y << 8) + x)) << 6)
                            + ((co * 2) ^ (((x >> 1) & 3) << 4));
                *(unsigned short*)((char*)at2 + byte) = f2bf(val);
            }
        }
    }
}

// ---------------- enh2: 3x3 conv 32->64 MFMA (half-row blocks) + bf16 residual + relu + bn4 stats ----------------
__global__ __launch_bounds__(256) void enh2_mfma(const unsigned short* __restrict__ at2,
                                                 const unsigned short* __restrict__ wb,  // [9][64][32]
                                                 const float* __restrict__ bias,
                                                 const unsigned short* __restrict__ ff,
                                                 unsigned short* __restrict__ enh,
                                                 float* __restrict__ st) {
    int bid = blockIdx.x;                  // 1024
    int orig = (bid & 7) * 128 + (bid >> 3);
    int hlf = orig & 1;
    int rowu = orig >> 1;
    int y = rowu & 255, b = rowu >> 8;
    int xb = hlf * 128;
    int tid = threadIdx.x;
    int lane = tid & 63, wid = tid >> 6;
    __shared__ __align__(16) unsigned short lds_u16[3 * 160 * 32];
    char* ldsb = (char*)lds_u16;
    {
        bf8v z = {0, 0, 0, 0, 0, 0, 0, 0};
        for (int i = tid; i < 3 * 160 * 32 / 8; i += 256) ((bf8v*)lds_u16)[i] = z;
    }
    __syncthreads();
    for (int c = wid; c < 30; c += 4) {
        int r = c / 10, k = c - r * 10;
        int yy = y + r - 1;
        int pxc = xb - 16 + k * 16;
        if ((unsigned)yy < 256u && (unsigned)pxc < 256u) {
            const char* src = (const char*)at2
                + (((size_t)((b << 16) + (yy << 8))) << 6)
                + (pxc + (lane >> 2)) * 64 + (lane & 3) * 16;
            char* dst = ldsb + r * 10240 + k * 1024;
            GLL16(src, dst);
        }
    }
    __syncthreads();
    f4v acc[2][4];
    {
        f4v z4 = {0.f, 0.f, 0.f, 0.f};
#pragma unroll
        for (int m = 0; m < 2; m++)
#pragma unroll
            for (int n = 0; n < 4; n++) acc[m][n] = z4;
    }
#pragma unroll
    for (int np = 0; np < 2; np++) {
        bf8v bw0[9], bw1[9];
#pragma unroll
        for (int pos = 0; pos < 9; pos++) {
            bw0[pos] = *(const bf8v*)(wb + (pos * 64 + np * 32 + (lane & 15)) * 32 + (lane >> 4) * 8);
            bw1[pos] = *(const bf8v*)(wb + (pos * 64 + np * 32 + 16 + (lane & 15)) * 32 + (lane >> 4) * 8);
        }
#pragma unroll
        for (int mt = 0; mt < 2; mt++) {
            int xg = xb + (wid * 2 + mt) * 16 + (lane & 15);
#pragma unroll
            for (int ky = 0; ky < 3; ky++) {
#pragma unroll
                for (int kx = 0; kx < 3; kx++) {
                    int x = xg + kx - 1;
                    int sl = x - xb + 16;
                    int off = (ky * 160 + sl) * 64 + (((lane >> 4) * 16) ^ (((x >> 1) & 3) << 4));
                    bf8v a = *(const bf8v*)(ldsb + off);
                    acc[mt][2 * np]     = __builtin_amdgcn_mfma_f32_16x16x32_bf16(a, bw0[ky * 3 + kx], acc[mt][2 * np], 0, 0, 0);
                    acc[mt][2 * np + 1] = __builtin_amdgcn_mfma_f32_16x16x32_bf16(a, bw1[ky * 3 + kx], acc[mt][2 * np + 1], 0, 0, 0);
                }
            }
        }
    }
    __syncthreads();
    float* red = (float*)lds_u16;  // [64 co][4 wave][2]
#pragma unroll
    for (int nt = 0; nt < 4; nt++) {
        int co = nt * 16 + (lane & 15);
        float bb = bias[co];
        float s = 0.f, q = 0.f;
#pragma unroll
        for (int mt = 0; mt < 2; mt++) {
            int xb4 = xb + (wid * 2 + mt) * 16 + (lane >> 4) * 4;
            size_t idx = ((size_t)(b * 64 + co) << 16) + (y << 8) + xb4;
            us4 rv = *(const us4*)(ff + idx);
            f4v a = acc[mt][nt];
            us4 ro;
            ro[0] = f2bf(fmaxf(a[0] + bb + bf2f(rv[0]), 0.f));
            ro[1] = f2bf(fmaxf(a[1] + bb + bf2f(rv[1]), 0.f));
            ro[2] = f2bf(fmaxf(a[2] + bb + bf2f(rv[2]), 0.f));
            ro[3] = f2bf(fmaxf(a[3] + bb + bf2f(rv[3]), 0.f));
            *(us4*)(enh + idx) = ro;
            float r0 = bf2f(ro[0]), r1 = bf2f(ro[1]), r2 = bf2f(ro[2]), r3 = bf2f(ro[3]);
            s += r0 + r1 + r2 + r3;
            q += r0 * r0 + r1 * r1 + r2 * r2 + r3 * r3;
        }
        s += __shfl_xor(s, 16); s += __shfl_xor(s, 32);
        q += __shfl_xor(q, 16); q += __shfl_xor(q, 32);
        if (lane < 16) {
            red[(co * 4 + wid) * 2 + 0] = s;
            red[(co * 4 + wid) * 2 + 1] = q;
        }
    }
    __syncthreads();
    if (tid < 64) {
        float s = 0.f, q = 0.f;
#pragma unroll
        for (int w = 0; w < 4; w++) {
            s += red[(tid * 4 + w) * 2 + 0];
            q += red[(tid * 4 + w) * 2 + 1];
        }
        atomicAdd(&st[tid], s);
        atomicAdd(&st[64 + tid], q);
    }
}

// ---------------- final BN apply: bf16 ENH -> fp32 d_out ----------------
__global__ void bn_apply4(const us4* __restrict__ enh, float4* __restrict__ io,
                          const float* __restrict__ raw,
                          const float* __restrict__ g, const float* __restrict__ b) {
    int t = blockIdx.x * 256 + threadIdx.x;
    int c = (t >> 14) & 63;
    float A, Bv;
    bn_coef(raw, g, b, 64, c, A, Bv);
    us4 v = enh[t];
    float4 o;
    o.x = fmaf(bf2f(v[0]), A, Bv);
    o.y = fmaf(bf2f(v[1]), A, Bv);
    o.z = fmaf(bf2f(v[2]), A, Bv);
    o.w = fmaf(bf2f(v[3]), A, Bv);
    io[t] = o;
}

extern "C" void kernel_launch(void* const* d_in, const int* in_sizes, int n_in,
                              void* d_out, int out_size, void* d_ws, size_t ws_size,
                              hipStream_t stream) {
    const float* x       = (const float*)d_in[0];
    const float* conv1_w = (const float*)d_in[1];
    const float* conv1_b = (const float*)d_in[2];
    const float* bn1_g   = (const float*)d_in[3];
    const float* bn1_b   = (const float*)d_in[4];
    const float* pos1_w  = (const float*)d_in[5];
    const float* pos1_b  = (const float*)d_in[6];
    const float* gat1_w  = (const float*)d_in[7];
    const float* gat1_as = (const float*)d_in[8];
    const float* gat1_ad = (const float*)d_in[9];
    const float* gat1_b  = (const float*)d_in[10];
    const float* bn2_g   = (const float*)d_in[11];
    const float* bn2_b   = (const float*)d_in[12];
    const float* pos2_w  = (const float*)d_in[13];
    const float* pos2_b  = (const float*)d_in[14];
    const float* gat2_w  = (const float*)d_in[15];
    const float* gat2_as = (const float*)d_in[16];
    const float* gat2_ad = (const float*)d_in[17];
    const float* gat2_b  = (const float*)d_in[18];
    const float* bn3_g   = (const float*)d_in[19];
    const float* bn3_b   = (const float*)d_in[20];
    const float* mlp1_w  = (const float*)d_in[21];
    const float* mlp1_b  = (const float*)d_in[22];
    const float* mlp2_w  = (const float*)d_in[23];
    const float* mlp2_b  = (const float*)d_in[24];
    const float* filt    = (const float*)d_in[25];
    const float* fbias   = (const float*)d_in[26];
    const float* enh1_w  = (const float*)d_in[27];
    const float* enh1_b  = (const float*)d_in[28];
    const float* enh2_w  = (const float*)d_in[29];
    const float* enh2_b  = (const float*)d_in[30];
    const float* bn4_g   = (const float*)d_in[31];
    const float* bn4_b   = (const float*)d_in[32];

    float* ws = (float*)d_ws;
    unsigned short* P0 = (unsigned short*)(ws + OFF_W0);   // A16 / G32 / G64 (bf16)
    unsigned short* HB = (unsigned short*)(ws + OFF_W1);   // H32 / H64 (bf16)
    unsigned short* FFB = (unsigned short*)(ws + OFF_W1);  // ff bf16 (after H dead)
    unsigned* AT1 = (unsigned*)(ws + OFF_W2);
    unsigned short* ENH = (unsigned short*)(ws + OFF_W2);  // enh bf16 (after AT1 dead)
    unsigned short* AT2 = (unsigned short*)(ws + OFF_W3);
    float* SB = ws + OFF_S;
    float* DB = ws + OFF_D;
    float* ST1 = ws + OFF_ST1;
    float* ST2 = ws + OFF_ST2;
    float* ST3 = ws + OFF_ST3;
    float* ST4 = ws + OFF_ST4;
    unsigned short* WB1 = (unsigned short*)(ws + OFF_WB1);
    unsigned short* WB2 = (unsigned short*)(ws + OFF_WB2);
    float* out = (float*)d_out;

    // 0. fused prep: zero stats + repack both enh weights
    prep<<<147, 256, 0, stream>>>(ws + OFF_STAT, enh1_w, WB1, enh2_w, WB2);

    // 1. conv1 5x5 + relu -> A16 bf16 (P0), fused bn1 stats
    conv5x5_all<<<dim3(256, 2), 256, 0, stream>>>(x, conv1_w, conv1_b, P0, ST1);

    // 2. gat1 pre -> H32 bf16 (HB), S, D
    gat_pre<16, 32><<<512, 256, 0, stream>>>(P0, ST1, bn1_g, bn1_b, pos1_w, pos1_b,
                                             gat1_w, gat1_as, gat1_ad, HB, SB, DB);

    // 3. gat1 stencil (MFMA, co-split) + relu -> G32 bf16 (P0), fused bn2 stats
    gat_stencil_mfma<32, false><<<1024, 256, 0, stream>>>(HB, SB, DB, gat1_b, P0, ST2);

    // 4. gat2 pre -> H64 bf16 (HB), S, D
    gat_pre<32, 64><<<512, 256, 0, stream>>>(P0, ST2, bn2_g, bn2_b, pos2_w, pos2_b,
                                             gat2_w, gat2_as, gat2_ad, HB, SB, DB);

    // 5. gat2 stencil (MFMA, co-split) + relu -> G64 bf16 (P0), fused bn3 stats + pooled
    gat_stencil_mfma<64, true><<<1024, 256, 0, stream>>>(HB, SB, DB, gat2_b, P0, ST3);

    // 6. ff (with fused MLP+softmax) -> FFB bf16 + AT1 swizzled
    ff_t<<<2048, 256, 0, stream>>>(P0, ST3, bn3_g, bn3_b, mlp1_w, mlp1_b, mlp2_w, mlp2_b,
                                   filt, fbias, FFB, AT1);

    // 7. enh1 MFMA (half-row) -> AT2
    enh1_mfma<<<1024, 256, 0, stream>>>((const unsigned short*)AT1, WB1, enh1_b, AT2);

    // 8. enh2 MFMA (half-row) + bf16 residual + relu -> ENH bf16, fused bn4 stats
    enh2_mfma<<<1024, 256, 0, stream>>>(AT2, WB2, enh2_b, FFB, ENH, ST4);

    // 9. bn4 apply: bf16 ENH -> fp32 d_out
    bn_apply4<<<8192, 256, 0, stream>>>((const us4*)ENH, (float4*)out, ST4, bn4_g, bn4_b);
}

// Round 12
// 193.346 us; speedup vs baseline: 1.0672x; 1.0672x over previous
//
#include <hip/hip_runtime.h>
#include <math.h>

#define HH 256
#define WW 256
#define NPIX 65536
#define BATCH 2

// ---------------- workspace layout (floats) ----------------
#define OFF_W0   0u                 // A16 bf16 / G32 bf16 / G64 bf16
#define OFF_W1   8388608u           // H32/H64 bf16, then FF bf16
#define OFF_W2   16777216u          // AT1 bf16 swizzled; later ENH bf16 [ch][px]
#define OFF_W3   20971520u          // AT2 bf16 swizzled
#define OFF_S    25165824u
#define OFF_D    25296896u
#define OFF_STAT 25427968u
#define OFF_ST1  (OFF_STAT + 0u)
#define OFF_ST2  (OFF_STAT + 64u)
#define OFF_ST3  (OFF_STAT + 192u)
#define OFF_ST4  (OFF_STAT + 448u)
#define STAT_ZERO_N 704
#define OFF_WB1  (OFF_STAT + 704u)            // bf16 [9][32][64] = 18432 u16
#define OFF_WB2  (OFF_WB1 + 18432u)           // bf16 [9][64][32] = 18432 u16

typedef __attribute__((ext_vector_type(8))) short bf8v;            // 8 bf16 = 16 B
typedef __attribute__((ext_vector_type(4))) float f4v;
typedef __attribute__((ext_vector_type(4))) unsigned short us4;    // 4 bf16 = 8 B

#define GLL16(g, l) __builtin_amdgcn_global_load_lds(                               \
    (const __attribute__((address_space(1))) unsigned int*)(g),                    \
    (__attribute__((address_space(3))) unsigned int*)(l), 16, 0, 0)

// ---------------- helpers ----------------
__device__ __forceinline__ unsigned short f2bf(float f) {
    unsigned u = __float_as_uint(f);
    return (unsigned short)((u + 0x7FFFu + ((u >> 16) & 1u)) >> 16);
}
__device__ __forceinline__ float bf2f(unsigned short u) {
    return __uint_as_float(((unsigned)u) << 16);
}

__device__ __forceinline__ void bn_coef(const float* __restrict__ raw,
                                        const float* __restrict__ g,
                                        const float* __restrict__ b,
                                        int C, int c, float& A, float& Bv) {
    const float inv = 1.f / (float)(BATCH * NPIX);
    float mu  = raw[c] * inv;
    float var = raw[C + c] * inv - mu * mu;
    float rinv = rsqrtf(var + 1e-5f);
    A  = g[c] * rinv;
    Bv = b[c] - A * mu;
}

__device__ __forceinline__ void wave_red2(float& s, float& q) {
#pragma unroll
    for (int off = 32; off; off >>= 1) {
        s += __shfl_xor(s, off);
        q += __shfl_xor(q, off);
    }
}

// XCD-aware remap for 512-block row grids: 64 consecutive rows per XCD chunk.
__device__ __forceinline__ void row_swz512(int bid, int& y, int& b) {
    int orig = (bid & 7) * 64 + (bid >> 3);
    y = orig & 255;
    b = orig >> 8;
}

// ---------------- fused prep: zero stats + both weight repacks ----------------
__global__ void prep(float* __restrict__ st,
                     const float* __restrict__ w1, unsigned short* __restrict__ wb1,
                     const float* __restrict__ w2, unsigned short* __restrict__ wb2) {
    int bid = blockIdx.x, tid = threadIdx.x;
    if (bid < 3) {
        int i = bid * 256 + tid;
        if (i < STAT_ZERO_N) st[i] = 0.f;
    } else if (bid < 75) {
        int i = (bid - 3) * 256 + tid;       // CO=32, CI=64
        int co = i / (64 * 9);
        int rem = i - co * 64 * 9;
        int ci = rem / 9;
        int pos = rem - ci * 9;
        wb1[(pos * 32 + co) * 64 + ci] = f2bf(w1[i]);
    } else {
        int i = (bid - 75) * 256 + tid;      // CO=64, CI=32
        int co = i / (32 * 9);
        int rem = i - co * 32 * 9;
        int ci = rem / 9;
        int pos = rem - ci * 9;
        wb2[(pos * 64 + co) * 32 + ci] = f2bf(w2[i]);
    }
}

// ---------------- conv1 5x5, 1->16, relu, bf16 out, fused bn1 stats ----------------
__global__ __launch_bounds__(256) void conv5x5_all(const float* __restrict__ x,
                                                   const float* __restrict__ w,
                                                   const float* __restrict__ bias,
                                                   unsigned short* __restrict__ out,
                                                   float* __restrict__ st) {
    int y = blockIdx.x, b = blockIdx.y;
    int xx = threadIdx.x;
    __shared__ float lds[5 * 260];
    __shared__ float red[2][16][4];
    for (int i = threadIdx.x; i < 5 * 260; i += 256) {
        int r = i / 260, pos = i - r * 260;
        int yy = y + r - 2, xc = pos - 2;
        float v = 0.f;
        if ((unsigned)yy < 256u && (unsigned)xc < 256u) v = x[(b << 16) + (yy << 8) + xc];
        lds[i] = v;
    }
    __syncthreads();
    float v[25];
#pragma unroll
    for (int r = 0; r < 5; r++)
#pragma unroll
        for (int c = 0; c < 5; c++) v[r * 5 + c] = lds[r * 260 + xx + c];
    int lane = threadIdx.x & 63, wv = threadIdx.x >> 6;
#pragma unroll
    for (int co = 0; co < 16; co++) {
        float acc = bias[co];
#pragma unroll
        for (int k = 0; k < 25; k++) acc = fmaf(v[k], w[co * 25 + k], acc);
        acc = fmaxf(acc, 0.f);
        out[((size_t)(b * 16 + co) << 16) + (y << 8) + xx] = f2bf(acc);
        float s = acc, q = acc * acc;
        wave_red2(s, q);
        if (lane == 0) { red[0][co][wv] = s; red[1][co][wv] = q; }
    }
    __syncthreads();
    if (threadIdx.x < 16) {
        int co = threadIdx.x;
        float s = red[0][co][0] + red[0][co][1] + red[0][co][2] + red[0][co][3];
        float q = red[1][co][0] + red[1][co][1] + red[1][co][2] + red[1][co][3];
        atomicAdd(&st[co], s);
        atomicAdd(&st[16 + co], q);
    }
}

// ---------------- GAT pre: bn + pos + h GEMM (bf16 in/out) + s/d ----------------
template <int CI, int CO>
__global__ __launch_bounds__(256) void gat_pre(const unsigned short* __restrict__ f,
                        const float* __restrict__ raw,
                        const float* __restrict__ bng, const float* __restrict__ bnb,
                        const float* __restrict__ posw, const float* __restrict__ posb,
                        const float* __restrict__ gw, const float* __restrict__ gas,
                        const float* __restrict__ gad,
                        unsigned short* __restrict__ hout, float* __restrict__ sout,
                        float* __restrict__ dout) {
    __shared__ float Ash[CI], Bsh[CI];
    if (threadIdx.x < CI) {
        float A, Bv;
        bn_coef(raw, bng, bnb, CI, threadIdx.x, A, Bv);
        Ash[threadIdx.x] = A;
        Bsh[threadIdx.x] = Bv + posb[threadIdx.x];
    }
    __syncthreads();
    int tid = blockIdx.x * 256 + threadIdx.x;
    int n = tid & (NPIX - 1);
    int b = tid >> 16;
    int y = n >> 8, x = n & 255;
    float py = y * (2.f / 255.f) - 1.f;
    float px = x * (2.f / 255.f) - 1.f;
    float v[CI];
#pragma unroll
    for (int ci = 0; ci < CI; ci++) {
        float t = fmaf(bf2f(f[(size_t)(b * CI + ci) * NPIX + n]), Ash[ci], Bsh[ci]);
        v[ci] = t + posw[2 * ci] * py + posw[2 * ci + 1] * px;
    }
    float s = 0.f, d = 0.f;
    for (int co = 0; co < CO; co++) {
        float acc = 0.f;
#pragma unroll
        for (int ci = 0; ci < CI; ci++) acc = fmaf(v[ci], gw[co * CI + ci], acc);
        hout[(size_t)(b * CO + co) * NPIX + n] = f2bf(acc);
        s = fmaf(acc, gas[co], s);
        d = fmaf(acc, gad[co], d);
    }
    sout[tid] = s;
    dout[tid] = d;
}

// ---------------- GAT stencil via MFMA, phase-split + CO-split ----------------
template <int CO, bool POOL>
__global__ __launch_bounds__(256) void gat_stencil_mfma(const unsigned short* __restrict__ hb,
                                                        const float* __restrict__ sbuf,
                                                        const float* __restrict__ dbuf,
                                                        const float* __restrict__ gb,
                                                        unsigned short* __restrict__ out,
                                                        float* __restrict__ st) {
    constexpr int NT2 = CO / 32;           // 16-ch tiles per wave (co-half)
    constexpr int CH = CO / 2;             // channels per half
    int bid = blockIdx.x;                  // 1024
    int orig = (bid & 7) * 128 + (bid >> 3);
    int coh = orig & 1;
    int rowu = orig >> 1;                  // [0,512)
    int y = rowu & 255;
    int b = rowu >> 8;
    int tid = threadIdx.x, lane = tid & 63, wid = tid >> 6;
    int m = lane & 15, grp = lane >> 4;
    int xw = wid * 64;                     // wave's 64-px span
    // ---- phase 1: per-pixel softmax ----
    int x = xw + lane;
    float di = dbuf[(b << 16) + (y << 8) + x];
    float p[9], mx = -1e30f;
#pragma unroll
    for (int k = 0; k < 9; k++) {
        int dy = k / 3 - 1, dx = k % 3 - 1;
        int yy = y + dy, xxn = x + dx;
        bool ok = ((unsigned)yy < 256u) && ((unsigned)xxn < 256u);
        float e = -1e30f;
        if (ok) {
            float t = sbuf[(b << 16) + (yy << 8) + xxn] + di;
            e = t > 0.f ? t : 0.2f * t;
        }
        p[k] = e;
        mx = fmaxf(mx, e);
    }
    float den = 0.f;
#pragma unroll
    for (int k = 0; k < 9; k++) { p[k] = __expf(p[k] - mx); den += p[k]; }
    float rden = 1.f / (den + 1e-16f);
    unsigned short pb[9];
#pragma unroll
    for (int k = 0; k < 9; k++) pb[k] = f2bf(p[k] * rden);
    unsigned pk0 = (unsigned)pb[0] | ((unsigned)pb[1] << 16);
    unsigned pk1 = (unsigned)pb[2] | ((unsigned)pb[3] << 16);
    unsigned pk2 = (unsigned)pb[4] | ((unsigned)pb[5] << 16);
    unsigned pk3 = (unsigned)pb[6] | ((unsigned)pb[7] << 16);
    unsigned pk4 = (unsigned)pb[8];
    float sAcc[NT2], qAcc[NT2], bb[NT2];
#pragma unroll
    for (int ct = 0; ct < NT2; ct++) {
        sAcc[ct] = 0.f; qAcc[ct] = 0.f;
        bb[ct] = gb[coh * CH + ct * 16 + m];
    }
    // ---- phase 2: 4 tiles ----
#pragma unroll 1
    for (int t = 0; t < 4; t++) {
        int xb = xw + t * 16;
        int src = t * 16 + m;
        unsigned rk0 = __shfl(pk0, src);
        unsigned rk1 = __shfl(pk1, src);
        unsigned rk2 = __shfl(pk2, src);
        unsigned rk3 = __shfl(pk3, src);
        unsigned rk4 = __shfl(pk4, src);
        unsigned short rb[9];
        rb[0] = (unsigned short)rk0; rb[1] = (unsigned short)(rk0 >> 16);
        rb[2] = (unsigned short)rk1; rb[3] = (unsigned short)(rk1 >> 16);
        rb[4] = (unsigned short)rk2; rb[5] = (unsigned short)(rk2 >> 16);
        rb[6] = (unsigned short)rk3; rb[7] = (unsigned short)(rk3 >> 16);
        rb[8] = (unsigned short)rk4;
        union { bf8v v; unsigned short h[8]; } af[3];
#pragma unroll
        for (int dyi = 0; dyi < 3; dyi++)
#pragma unroll
            for (int j = 0; j < 8; j++) {
                int k = grp * 8 + j;
                int d = k - 8 - m;
                af[dyi].h[j] = (d >= -1 && d <= 1) ? rb[dyi * 3 + d + 1] : (unsigned short)0;
            }
        f4v acc[NT2];
        f4v z4 = {0.f, 0.f, 0.f, 0.f};
#pragma unroll
        for (int ct = 0; ct < NT2; ct++) acc[ct] = z4;
        int px0 = xb - 8 + grp * 8;
        px0 = px0 < 0 ? 0 : (px0 > 248 ? 248 : px0);
#pragma unroll
        for (int dyi = 0; dyi < 3; dyi++) {
            int yy = y + dyi - 1;
            if ((unsigned)yy >= 256u) continue;
#pragma unroll
            for (int ct = 0; ct < NT2; ct++) {
                int ch = coh * CH + ct * 16 + m;
                bf8v bv = *(const bf8v*)(hb + (((size_t)(b * CO + ch)) << 16) + (yy << 8) + px0);
                acc[ct] = __builtin_amdgcn_mfma_f32_16x16x32_bf16(af[dyi].v, bv, acc[ct], 0, 0, 0);
            }
        }
        int pxr = xb + grp * 4;
#pragma unroll
        for (int ct = 0; ct < NT2; ct++) {
            int ch = coh * CH + ct * 16 + m;
            f4v a = acc[ct];
            float o0 = fmaxf(a[0] + bb[ct], 0.f);
            float o1 = fmaxf(a[1] + bb[ct], 0.f);
            float o2 = fmaxf(a[2] + bb[ct], 0.f);
            float o3 = fmaxf(a[3] + bb[ct], 0.f);
            us4 pkst = {f2bf(o0), f2bf(o1), f2bf(o2), f2bf(o3)};
            *(us4*)(out + (((size_t)(b * CO + ch)) << 16) + (y << 8) + pxr) = pkst;
            sAcc[ct] += o0 + o1 + o2 + o3;
            qAcc[ct] += o0 * o0 + o1 * o1 + o2 * o2 + o3 * o3;
        }
    }
    // ---- stats ----
#pragma unroll
    for (int ct = 0; ct < NT2; ct++) {
        sAcc[ct] += __shfl_xor(sAcc[ct], 16); sAcc[ct] += __shfl_xor(sAcc[ct], 32);
        qAcc[ct] += __shfl_xor(qAcc[ct], 16); qAcc[ct] += __shfl_xor(qAcc[ct], 32);
    }
    __shared__ float red[2][NT2][16][4];
    if (grp == 0) {
#pragma unroll
        for (int ct = 0; ct < NT2; ct++) {
            red[0][ct][m][wid] = sAcc[ct];
            red[1][ct][m][wid] = qAcc[ct];
        }
    }
    __syncthreads();
    if (tid < CH) {
        int ct = tid >> 4, mm = tid & 15;
        int c = coh * CH + tid;
        float s = red[0][ct][mm][0] + red[0][ct][mm][1] + red[0][ct][mm][2] + red[0][ct][mm][3];
        float qq = red[1][ct][mm][0] + red[1][ct][mm][1] + red[1][ct][mm][2] + red[1][ct][mm][3];
        atomicAdd(&st[c], s);
        atomicAdd(&st[CO + c], qq);
        if (POOL) atomicAdd(&st[2 * CO + b * CO + c], s);
    }
}

// ---------------- ff (bf16 out) + transpose + FUSED channel-weight MLP ----------------
__global__ __launch_bounds__(256) void ff_t(const unsigned short* __restrict__ g64,
                                            const float* __restrict__ raw3,
                                            const float* __restrict__ g3,
                                            const float* __restrict__ b3,
                                            const float* __restrict__ w1,
                                            const float* __restrict__ bb1,
                                            const float* __restrict__ w2,
                                            const float* __restrict__ bb2,
                                            const float* __restrict__ filt,
                                            const float* __restrict__ fbias,
                                            unsigned short* __restrict__ ffout,
                                            unsigned* __restrict__ at1) {
    __shared__ float pooled[2][64];
    __shared__ float hsh[2][16];
    __shared__ float cwsh[2][64];
    __shared__ unsigned t[64 * 33];
    int tid = threadIdx.x;
    if (tid < 128) {
        int b = tid >> 6, c = tid & 63;
        float A, Bv;
        bn_coef(raw3, g3, b3, 64, c, A, Bv);
        float sm = raw3[128 + (b << 6) + c];
        pooled[b][c] = fmaf(sm * (1.f / 65536.f), A, Bv);
    }
    __syncthreads();
    if (tid < 32) {
        int b = tid >> 4, j = tid & 15;
        float acc = bb1[j];
        for (int c2 = 0; c2 < 64; c2++) acc = fmaf(pooled[b][c2], w1[(j << 6) + c2], acc);
        hsh[b][j] = fmaxf(acc, 0.f);
    }
    __syncthreads();
    if (tid < 128) {
        int b = tid >> 6, c = tid & 63;
        float logit = bb2[c];
        for (int j = 0; j < 16; j++) logit = fmaf(hsh[b][j], w2[(c << 4) + j], logit);
        float mm = logit;
#pragma unroll
        for (int off = 32; off; off >>= 1) mm = fmaxf(mm, __shfl_xor(mm, off));
        float e = __expf(logit - mm);
        float ss = e;
#pragma unroll
        for (int off = 32; off; off >>= 1) ss += __shfl_xor(ss, off);
        cwsh[b][c] = e / ss;
    }
    __syncthreads();
    int pxb = blockIdx.x * 64;
    int b = pxb >> 16;
    int nb = pxb & 65535;
#pragma unroll
    for (int k = 0; k < 2; k++) {
        int u = tid + k * 256;
        int q = u & 15;
        int cp = u >> 4;
        int ch0 = cp * 2, ch1 = ch0 + 1;
        float A0, B0, A1, B1;
        bn_coef(raw3, g3, b3, 64, ch0, A0, B0);
        bn_coef(raw3, g3, b3, 64, ch1, A1, B1);
        float s0 = cwsh[b][ch0], s1 = cwsh[b][ch1];
        float fb0 = fbias[ch0], fb1 = fbias[ch1];
        int n = nb + q * 4;
        us4 r0 = *(const us4*)(g64 + ((size_t)(b * 64 + ch0) << 16) + n);
        us4 r1 = *(const us4*)(g64 + ((size_t)(b * 64 + ch1) << 16) + n);
        float4 l0 = *(const float4*)(filt + ((size_t)ch0 << 16) + n);
        float4 l1 = *(const float4*)(filt + ((size_t)ch1 << 16) + n);
        float4 o0, o1;
        o0.x = fmaf(fmaf(bf2f(r0[0]), A0, B0) * s0, l0.x, fb0);
        o0.y = fmaf(fmaf(bf2f(r0[1]), A0, B0) * s0, l0.y, fb0);
        o0.z = fmaf(fmaf(bf2f(r0[2]), A0, B0) * s0, l0.z, fb0);
        o0.w = fmaf(fmaf(bf2f(r0[3]), A0, B0) * s0, l0.w, fb0);
        o1.x = fmaf(fmaf(bf2f(r1[0]), A1, B1) * s1, l1.x, fb1);
        o1.y = fmaf(fmaf(bf2f(r1[1]), A1, B1) * s1, l1.y, fb1);
        o1.z = fmaf(fmaf(bf2f(r1[2]), A1, B1) * s1, l1.z, fb1);
        o1.w = fmaf(fmaf(bf2f(r1[3]), A1, B1) * s1, l1.w, fb1);
        us4 f0 = {f2bf(o0.x), f2bf(o0.y), f2bf(o0.z), f2bf(o0.w)};
        us4 f1 = {f2bf(o1.x), f2bf(o1.y), f2bf(o1.z), f2bf(o1.w)};
        *(us4*)(ffout + ((size_t)(b * 64 + ch0) << 16) + n) = f0;
        *(us4*)(ffout + ((size_t)(b * 64 + ch1) << 16) + n) = f1;
#pragma unroll
        for (int i = 0; i < 4; i++)
            t[(q * 4 + i) * 33 + cp] = (unsigned)f0[i] | ((unsigned)f1[i] << 16);
    }
    __syncthreads();
#pragma unroll
    for (int j = 0; j < 8; j++) {
        int lin = j * 256 + tid;
        int pl = lin >> 5, cp = lin & 31;
        unsigned v = t[pl * 33 + cp];
        int P = pxb + pl;
        size_t byte = ((size_t)P << 7) + ((cp >= 16) ? 64 : 0)
                    + (((cp & 15) * 4) ^ (((P >> 1) & 3) << 4));
        *(unsigned*)((char*)at1 + byte) = v;
    }
}

// ---------------- enh1: 3x3 conv 64->32 via MFMA, 8 waves/row, relu, bf16 out ----------------
__global__ __launch_bounds__(512) void enh1_mfma(const unsigned short* __restrict__ at1,
                                                 const unsigned short* __restrict__ wb,  // [9][32][64]
                                                 const float* __restrict__ bias,
                                                 unsigned short* __restrict__ at2) {
    int y, b;
    row_swz512(blockIdx.x, y, b);
    int tid = threadIdx.x;
    int lane = tid & 63, wid = tid >> 6;   // wid in [0,8)
    __shared__ __align__(16) unsigned short lds_u16[3 * 258 * 32];
    char* ldsb = (char*)lds_u16;
    {
        bf8v z = {0, 0, 0, 0, 0, 0, 0, 0};
        for (int i = tid; i < 3 * 258 * 32 / 8; i += 512) ((bf8v*)lds_u16)[i] = z;
    }
    f4v acc[2][2];
    {
        f4v z4 = {0.f, 0.f, 0.f, 0.f};
#pragma unroll
        for (int m = 0; m < 2; m++) { acc[m][0] = z4; acc[m][1] = z4; }
    }
#pragma unroll 1
    for (int kh = 0; kh < 2; kh++) {
        __syncthreads();
        for (int c = wid; c < 48; c += 8) {
            int r = c >> 4, k = c & 15;
            int yy = y + r - 1;
            if ((unsigned)yy < 256u) {
                const char* src = (const char*)at1
                    + (((size_t)((b << 16) + (yy << 8)) + (k * 16 + (lane >> 2))) << 7)
                    + kh * 64 + (lane & 3) * 16;
                char* dst = ldsb + (r * 258 + 1) * 64 + k * 1024;
                GLL16(src, dst);
            }
        }
        __syncthreads();
        bf8v bw0[9], bw1[9];
#pragma unroll
        for (int pos = 0; pos < 9; pos++) {
            bw0[pos] = *(const bf8v*)(wb + (pos * 32 + (lane & 15)) * 64 + kh * 32 + (lane >> 4) * 8);
            bw1[pos] = *(const bf8v*)(wb + (pos * 32 + 16 + (lane & 15)) * 64 + kh * 32 + (lane >> 4) * 8);
        }
#pragma unroll
        for (int mt = 0; mt < 2; mt++) {
            int xb = (wid * 2 + mt) * 16 + (lane & 15);
#pragma unroll
            for (int ky = 0; ky < 3; ky++) {
#pragma unroll
                for (int kx = 0; kx < 3; kx++) {
                    int x = xb + kx - 1;
                    int s = x + 1;
                    int off = (ky * 258 + s) * 64 + (((lane >> 4) * 16) ^ (((x >> 1) & 3) << 4));
                    bf8v a = *(const bf8v*)(ldsb + off);
                    acc[mt][0] = __builtin_amdgcn_mfma_f32_16x16x32_bf16(a, bw0[ky * 3 + kx], acc[mt][0], 0, 0, 0);
                    acc[mt][1] = __builtin_amdgcn_mfma_f32_16x16x32_bf16(a, bw1[ky * 3 + kx], acc[mt][1], 0, 0, 0);
                }
            }
        }
    }
    float bb[2] = {bias[lane & 15], bias[16 + (lane & 15)]};
#pragma unroll
    for (int mt = 0; mt < 2; mt++) {
#pragma unroll
        for (int nt = 0; nt < 2; nt++) {
            f4v v = acc[mt][nt];
            int co = nt * 16 + (lane & 15);
#pragma unroll
            for (int r = 0; r < 4; r++) {
                int x = (wid * 2 + mt) * 16 + (lane >> 4) * 4 + r;
                float val = fmaxf(v[r] + bb[nt], 0.f);
                size_t byte = (((size_t)((b << 16) + (y << 8) + x)) << 6)
                            + ((co * 2) ^ (((x >> 1) & 3) << 4));
                *(unsigned short*)((char*)at2 + byte) = f2bf(val);
            }
        }
    }
}

// ---------------- enh2: 3x3 conv 32->64 MFMA, 8 waves/row + bf16 residual + relu + bn4 stats ----------------
__global__ __launch_bounds__(512) void enh2_mfma(const unsigned short* __restrict__ at2,
                                                 const unsigned short* __restrict__ wb,  // [9][64][32]
                                                 const float* __restrict__ bias,
                                                 const unsigned short* __restrict__ ff,
                                                 unsigned short* __restrict__ enh,
                                                 float* __restrict__ st) {
    int y, b;
    row_swz512(blockIdx.x, y, b);
    int tid = threadIdx.x;
    int lane = tid & 63, wid = tid >> 6;   // wid in [0,8)
    __shared__ __align__(16) unsigned short lds_u16[3 * 258 * 32];
    char* ldsb = (char*)lds_u16;
    {
        bf8v z = {0, 0, 0, 0, 0, 0, 0, 0};
        for (int i = tid; i < 3 * 258 * 32 / 8; i += 512) ((bf8v*)lds_u16)[i] = z;
    }
    __syncthreads();
    for (int c = wid; c < 48; c += 8) {
        int r = c >> 4, k = c & 15;
        int yy = y + r - 1;
        if ((unsigned)yy < 256u) {
            const char* src = (const char*)at2
                + (((size_t)((b << 16) + (yy << 8))) << 6) + k * 1024 + lane * 16;
            char* dst = ldsb + (r * 258 + 1) * 64 + k * 1024;
            GLL16(src, dst);
        }
    }
    __syncthreads();
    f4v acc[2][4];
    {
        f4v z4 = {0.f, 0.f, 0.f, 0.f};
#pragma unroll
        for (int m = 0; m < 2; m++)
#pragma unroll
            for (int n = 0; n < 4; n++) acc[m][n] = z4;
    }
#pragma unroll
    for (int np = 0; np < 2; np++) {
        bf8v bw0[9], bw1[9];
#pragma unroll
        for (int pos = 0; pos < 9; pos++) {
            bw0[pos] = *(const bf8v*)(wb + (pos * 64 + np * 32 + (lane & 15)) * 32 + (lane >> 4) * 8);
            bw1[pos] = *(const bf8v*)(wb + (pos * 64 + np * 32 + 16 + (lane & 15)) * 32 + (lane >> 4) * 8);
        }
#pragma unroll
        for (int mt = 0; mt < 2; mt++) {
            int xb = (wid * 2 + mt) * 16 + (lane & 15);
#pragma unroll
            for (int ky = 0; ky < 3; ky++) {
#pragma unroll
                for (int kx = 0; kx < 3; kx++) {
                    int x = xb + kx - 1;
                    int s = x + 1;
                    int off = (ky * 258 + s) * 64 + (((lane >> 4) * 16) ^ (((x >> 1) & 3) << 4));
                    bf8v a = *(const bf8v*)(ldsb + off);
                    acc[mt][2 * np]     = __builtin_amdgcn_mfma_f32_16x16x32_bf16(a, bw0[ky * 3 + kx], acc[mt][2 * np], 0, 0, 0);
                    acc[mt][2 * np + 1] = __builtin_amdgcn_mfma_f32_16x16x32_bf16(a, bw1[ky * 3 + kx], acc[mt][2 * np + 1], 0, 0, 0);
                }
            }
        }
    }
    __syncthreads();
    float* red = (float*)lds_u16;  // [64 co][8 wave][2]
#pragma unroll
    for (int nt = 0; nt < 4; nt++) {
        int co = nt * 16 + (lane & 15);
        float bb = bias[co];
        float s = 0.f, q = 0.f;
#pragma unroll
        for (int mt = 0; mt < 2; mt++) {
            int xb4 = (wid * 2 + mt) * 16 + (lane >> 4) * 4;
            size_t idx = ((size_t)(b * 64 + co) << 16) + (y << 8) + xb4;
            us4 rv = *(const us4*)(ff + idx);
            f4v a = acc[mt][nt];
            us4 ro;
            ro[0] = f2bf(fmaxf(a[0] + bb + bf2f(rv[0]), 0.f));
            ro[1] = f2bf(fmaxf(a[1] + bb + bf2f(rv[1]), 0.f));
            ro[2] = f2bf(fmaxf(a[2] + bb + bf2f(rv[2]), 0.f));
            ro[3] = f2bf(fmaxf(a[3] + bb + bf2f(rv[3]), 0.f));
            *(us4*)(enh + idx) = ro;
            float r0 = bf2f(ro[0]), r1 = bf2f(ro[1]), r2 = bf2f(ro[2]), r3 = bf2f(ro[3]);
            s += r0 + r1 + r2 + r3;
            q += r0 * r0 + r1 * r1 + r2 * r2 + r3 * r3;
        }
        s += __shfl_xor(s, 16); s += __shfl_xor(s, 32);
        q += __shfl_xor(q, 16); q += __shfl_xor(q, 32);
        if (lane < 16) {
            red[(co * 8 + wid) * 2 + 0] = s;
            red[(co * 8 + wid) * 2 + 1] = q;
        }
    }
    __syncthreads();
    if (tid < 64) {
        float s = 0.f, q = 0.f;
#pragma unroll
        for (int w = 0; w < 8; w++) {
            s += red[(tid * 8 + w) * 2 + 0];
            q += red[(tid * 8 + w) * 2 + 1];
        }
        atomicAdd(&st[tid], s);
        atomicAdd(&st[64 + tid], q);
    }
}

// ---------------- final BN apply: bf16 ENH -> fp32 d_out ----------------
__global__ void bn_apply4(const us4* __restrict__ enh, float4* __restrict__ io,
                          const float* __restrict__ raw,
                          const float* __restrict__ g, const float* __restrict__ b) {
    int t = blockIdx.x * 256 + threadIdx.x;
    int c = (t >> 14) & 63;
    float A, Bv;
    bn_coef(raw, g, b, 64, c, A, Bv);
    us4 v = enh[t];
    float4 o;
    o.x = fmaf(bf2f(v[0]), A, Bv);
    o.y = fmaf(bf2f(v[1]), A, Bv);
    o.z = fmaf(bf2f(v[2]), A, Bv);
    o.w = fmaf(bf2f(v[3]), A, Bv);
    io[t] = o;
}

extern "C" void kernel_launch(void* const* d_in, const int* in_sizes, int n_in,
                              void* d_out, int out_size, void* d_ws, size_t ws_size,
                              hipStream_t stream) {
    const float* x       = (const float*)d_in[0];
    const float* conv1_w = (const float*)d_in[1];
    const float* conv1_b = (const float*)d_in[2];
    const float* bn1_g   = (const float*)d_in[3];
    const float* bn1_b   = (const float*)d_in[4];
    const float* pos1_w  = (const float*)d_in[5];
    const float* pos1_b  = (const float*)d_in[6];
    const float* gat1_w  = (const float*)d_in[7];
    const float* gat1_as = (const float*)d_in[8];
    const float* gat1_ad = (const float*)d_in[9];
    const float* gat1_b  = (const float*)d_in[10];
    const float* bn2_g   = (const float*)d_in[11];
    const float* bn2_b   = (const float*)d_in[12];
    const float* pos2_w  = (const float*)d_in[13];
    const float* pos2_b  = (const float*)d_in[14];
    const float* gat2_w  = (const float*)d_in[15];
    const float* gat2_as = (const float*)d_in[16];
    const float* gat2_ad = (const float*)d_in[17];
    const float* gat2_b  = (const float*)d_in[18];
    const float* bn3_g   = (const float*)d_in[19];
    const float* bn3_b   = (const float*)d_in[20];
    const float* mlp1_w  = (const float*)d_in[21];
    const float* mlp1_b  = (const float*)d_in[22];
    const float* mlp2_w  = (const float*)d_in[23];
    const float* mlp2_b  = (const float*)d_in[24];
    const float* filt    = (const float*)d_in[25];
    const float* fbias   = (const float*)d_in[26];
    const float* enh1_w  = (const float*)d_in[27];
    const float* enh1_b  = (const float*)d_in[28];
    const float* enh2_w  = (const float*)d_in[29];
    const float* enh2_b  = (const float*)d_in[30];
    const float* bn4_g   = (const float*)d_in[31];
    const float* bn4_b   = (const float*)d_in[32];

    float* ws = (float*)d_ws;
    unsigned short* P0 = (unsigned short*)(ws + OFF_W0);   // A16 / G32 / G64 (bf16)
    unsigned short* HB = (unsigned short*)(ws + OFF_W1);   // H32 / H64 (bf16)
    unsigned short* FFB = (unsigned short*)(ws + OFF_W1);  // ff bf16 (after H dead)
    unsigned* AT1 = (unsigned*)(ws + OFF_W2);
    unsigned short* ENH = (unsigned short*)(ws + OFF_W2);  // enh bf16 (after AT1 dead)
    unsigned short* AT2 = (unsigned short*)(ws + OFF_W3);
    float* SB = ws + OFF_S;
    float* DB = ws + OFF_D;
    float* ST1 = ws + OFF_ST1;
    float* ST2 = ws + OFF_ST2;
    float* ST3 = ws + OFF_ST3;
    float* ST4 = ws + OFF_ST4;
    unsigned short* WB1 = (unsigned short*)(ws + OFF_WB1);
    unsigned short* WB2 = (unsigned short*)(ws + OFF_WB2);
    float* out = (float*)d_out;

    // 0. fused prep: zero stats + repack both enh weights
    prep<<<147, 256, 0, stream>>>(ws + OFF_STAT, enh1_w, WB1, enh2_w, WB2);

    // 1. conv1 5x5 + relu -> A16 bf16 (P0), fused bn1 stats
    conv5x5_all<<<dim3(256, 2), 256, 0, stream>>>(x, conv1_w, conv1_b, P0, ST1);

    // 2. gat1 pre -> H32 bf16 (HB), S, D
    gat_pre<16, 32><<<512, 256, 0, stream>>>(P0, ST1, bn1_g, bn1_b, pos1_w, pos1_b,
                                             gat1_w, gat1_as, gat1_ad, HB, SB, DB);

    // 3. gat1 stencil (MFMA, co-split) + relu -> G32 bf16 (P0), fused bn2 stats
    gat_stencil_mfma<32, false><<<1024, 256, 0, stream>>>(HB, SB, DB, gat1_b, P0, ST2);

    // 4. gat2 pre -> H64 bf16 (HB), S, D
    gat_pre<32, 64><<<512, 256, 0, stream>>>(P0, ST2, bn2_g, bn2_b, pos2_w, pos2_b,
                                             gat2_w, gat2_as, gat2_ad, HB, SB, DB);

    // 5. gat2 stencil (MFMA, co-split) + relu -> G64 bf16 (P0), fused bn3 stats + pooled
    gat_stencil_mfma<64, true><<<1024, 256, 0, stream>>>(HB, SB, DB, gat2_b, P0, ST3);

    // 6. ff (with fused MLP+softmax) -> FFB bf16 + AT1 swizzled
    ff_t<<<2048, 256, 0, stream>>>(P0, ST3, bn3_g, bn3_b, mlp1_w, mlp1_b, mlp2_w, mlp2_b,
                                   filt, fbias, FFB, AT1);

    // 7. enh1 MFMA (8 waves/row) -> AT2
    enh1_mfma<<<512, 512, 0, stream>>>((const unsigned short*)AT1, WB1, enh1_b, AT2);

    // 8. enh2 MFMA (8 waves/row) + bf16 residual + relu -> ENH bf16, fused bn4 stats
    enh2_mfma<<<512, 512, 0, stream>>>(AT2, WB2, enh2_b, FFB, ENH, ST4);

    // 9. bn4 apply: bf16 ENH -> fp32 d_out
    bn_apply4<<<8192, 256, 0, stream>>>((const us4*)ENH, (float4*)out, ST4, bn4_g, bn4_b);
}

// Round 13
// 172.372 us; speedup vs baseline: 1.1970x; 1.1217x over previous
//
#include <hip/hip_runtime.h>
#include <math.h>

#define HH 256
#define WW 256
#define NPIX 65536
#define BATCH 2

// ---------------- workspace layout (floats) ----------------
#define OFF_W0   0u                 // A16 bf16 / G32 bf16 / G64 bf16
#define OFF_W1   8388608u           // H32/H64 bf16, then FF bf16
#define OFF_W2   16777216u          // AT1 bf16 swizzled; later ENH bf16 [ch][px]
#define OFF_W3   20971520u          // SB1/DB1 during GAT phase; AT2 during enh phase
#define OFF_S    25165824u
#define OFF_D    25296896u
#define OFF_STAT 25427968u
#define OFF_ST1  (OFF_STAT + 0u)
#define OFF_ST2  (OFF_STAT + 64u)
#define OFF_ST3  (OFF_STAT + 192u)
#define OFF_ST4  (OFF_STAT + 448u)
#define STAT_ZERO_N 704
#define OFF_WB1  (OFF_STAT + 704u)            // bf16 [9][32][64] = 18432 u16
#define OFF_WB2  (OFF_WB1 + 18432u)           // bf16 [9][64][32] = 18432 u16

typedef __attribute__((ext_vector_type(8))) short bf8v;            // 8 bf16 = 16 B
typedef __attribute__((ext_vector_type(4))) float f4v;
typedef __attribute__((ext_vector_type(4))) unsigned short us4;    // 4 bf16 = 8 B

#define GLL16(g, l) __builtin_amdgcn_global_load_lds(                               \
    (const __attribute__((address_space(1))) unsigned int*)(g),                    \
    (__attribute__((address_space(3))) unsigned int*)(l), 16, 0, 0)

// ---------------- helpers ----------------
__device__ __forceinline__ unsigned short f2bf(float f) {
    unsigned u = __float_as_uint(f);
    return (unsigned short)((u + 0x7FFFu + ((u >> 16) & 1u)) >> 16);
}
__device__ __forceinline__ float bf2f(unsigned short u) {
    return __uint_as_float(((unsigned)u) << 16);
}

__device__ __forceinline__ void bn_coef(const float* __restrict__ raw,
                                        const float* __restrict__ g,
                                        const float* __restrict__ b,
                                        int C, int c, float& A, float& Bv) {
    const float inv = 1.f / (float)(BATCH * NPIX);
    float mu  = raw[c] * inv;
    float var = raw[C + c] * inv - mu * mu;
    float rinv = rsqrtf(var + 1e-5f);
    A  = g[c] * rinv;
    Bv = b[c] - A * mu;
}

__device__ __forceinline__ void wave_red2(float& s, float& q) {
#pragma unroll
    for (int off = 32; off; off >>= 1) {
        s += __shfl_xor(s, off);
        q += __shfl_xor(q, off);
    }
}

// XCD-aware remap for 512-block row grids: 64 consecutive rows per XCD chunk.
__device__ __forceinline__ void row_swz512(int bid, int& y, int& b) {
    int orig = (bid & 7) * 64 + (bid >> 3);
    y = orig & 255;
    b = orig >> 8;
}

// ---------------- fused prep: zero stats + both weight repacks ----------------
__global__ void prep(float* __restrict__ st,
                     const float* __restrict__ w1, unsigned short* __restrict__ wb1,
                     const float* __restrict__ w2, unsigned short* __restrict__ wb2) {
    int bid = blockIdx.x, tid = threadIdx.x;
    if (bid < 3) {
        int i = bid * 256 + tid;
        if (i < STAT_ZERO_N) st[i] = 0.f;
    } else if (bid < 75) {
        int i = (bid - 3) * 256 + tid;       // CO=32, CI=64
        int co = i / (64 * 9);
        int rem = i - co * 64 * 9;
        int ci = rem / 9;
        int pos = rem - ci * 9;
        wb1[(pos * 32 + co) * 64 + ci] = f2bf(w1[i]);
    } else {
        int i = (bid - 75) * 256 + tid;      // CO=64, CI=32
        int co = i / (32 * 9);
        int rem = i - co * 32 * 9;
        int ci = rem / 9;
        int pos = rem - ci * 9;
        wb2[(pos * 64 + co) * 32 + ci] = f2bf(w2[i]);
    }
}

// ---------------- conv1 5x5, 1->16, relu, bf16 out, fused bn1 stats ----------------
__global__ __launch_bounds__(256) void conv5x5_all(const float* __restrict__ x,
                                                   const float* __restrict__ w,
                                                   const float* __restrict__ bias,
                                                   unsigned short* __restrict__ out,
                                                   float* __restrict__ st) {
    int y = blockIdx.x, b = blockIdx.y;
    int xx = threadIdx.x;
    __shared__ float lds[5 * 260];
    __shared__ float red[2][16][4];
    for (int i = threadIdx.x; i < 5 * 260; i += 256) {
        int r = i / 260, pos = i - r * 260;
        int yy = y + r - 2, xc = pos - 2;
        float v = 0.f;
        if ((unsigned)yy < 256u && (unsigned)xc < 256u) v = x[(b << 16) + (yy << 8) + xc];
        lds[i] = v;
    }
    __syncthreads();
    float v[25];
#pragma unroll
    for (int r = 0; r < 5; r++)
#pragma unroll
        for (int c = 0; c < 5; c++) v[r * 5 + c] = lds[r * 260 + xx + c];
    int lane = threadIdx.x & 63, wv = threadIdx.x >> 6;
#pragma unroll
    for (int co = 0; co < 16; co++) {
        float acc = bias[co];
#pragma unroll
        for (int k = 0; k < 25; k++) acc = fmaf(v[k], w[co * 25 + k], acc);
        acc = fmaxf(acc, 0.f);
        out[((size_t)(b * 16 + co) << 16) + (y << 8) + xx] = f2bf(acc);
        float s = acc, q = acc * acc;
        wave_red2(s, q);
        if (lane == 0) { red[0][co][wv] = s; red[1][co][wv] = q; }
    }
    __syncthreads();
    if (threadIdx.x < 16) {
        int co = threadIdx.x;
        float s = red[0][co][0] + red[0][co][1] + red[0][co][2] + red[0][co][3];
        float q = red[1][co][0] + red[1][co][1] + red[1][co][2] + red[1][co][3];
        atomicAdd(&st[co], s);
        atomicAdd(&st[16 + co], q);
    }
}

// ---------------- GAT pre (co-split): bn + pos + h GEMM half + partial s/d ----------------
// grid (512, 2): blockIdx.y = co-half. Partial s/d written non-atomically to
// per-half buffers; the stencil sums the two halves.
template <int CI, int CO>
__global__ __launch_bounds__(256) void gat_pre(const unsigned short* __restrict__ f,
                        const float* __restrict__ raw,
                        const float* __restrict__ bng, const float* __restrict__ bnb,
                        const float* __restrict__ posw, const float* __restrict__ posb,
                        const float* __restrict__ gw, const float* __restrict__ gas,
                        const float* __restrict__ gad,
                        unsigned short* __restrict__ hout,
                        float* __restrict__ s0, float* __restrict__ d0,
                        float* __restrict__ s1, float* __restrict__ d1) {
    constexpr int CH = CO / 2;
    int coh = blockIdx.y;
    __shared__ float Ash[CI], Bsh[CI];
    if (threadIdx.x < CI) {
        float A, Bv;
        bn_coef(raw, bng, bnb, CI, threadIdx.x, A, Bv);
        Ash[threadIdx.x] = A;
        Bsh[threadIdx.x] = Bv + posb[threadIdx.x];
    }
    __syncthreads();
    int tid = blockIdx.x * 256 + threadIdx.x;
    int n = tid & (NPIX - 1);
    int b = tid >> 16;
    int y = n >> 8, x = n & 255;
    float py = y * (2.f / 255.f) - 1.f;
    float px = x * (2.f / 255.f) - 1.f;
    float v[CI];
#pragma unroll
    for (int ci = 0; ci < CI; ci++) {
        float t = fmaf(bf2f(f[(size_t)(b * CI + ci) * NPIX + n]), Ash[ci], Bsh[ci]);
        v[ci] = t + posw[2 * ci] * py + posw[2 * ci + 1] * px;
    }
    float s = 0.f, d = 0.f;
    for (int cc = 0; cc < CH; cc++) {
        int co = coh * CH + cc;
        float acc = 0.f;
#pragma unroll
        for (int ci = 0; ci < CI; ci++) acc = fmaf(v[ci], gw[co * CI + ci], acc);
        hout[(size_t)(b * CO + co) * NPIX + n] = f2bf(acc);
        s = fmaf(acc, gas[co], s);
        d = fmaf(acc, gad[co], d);
    }
    float* so = coh ? s1 : s0;
    float* dd = coh ? d1 : d0;
    so[tid] = s;
    dd[tid] = d;
}

// ---------------- GAT stencil via MFMA, phase-split + CO-split (dual s/d) ----------------
template <int CO, bool POOL>
__global__ __launch_bounds__(256) void gat_stencil_mfma(const unsigned short* __restrict__ hb,
                                                        const float* __restrict__ sb0,
                                                        const float* __restrict__ sb1,
                                                        const float* __restrict__ db0,
                                                        const float* __restrict__ db1,
                                                        const float* __restrict__ gb,
                                                        unsigned short* __restrict__ out,
                                                        float* __restrict__ st) {
    constexpr int NT2 = CO / 32;           // 16-ch tiles per wave (co-half)
    constexpr int CH = CO / 2;             // channels per half
    int bid = blockIdx.x;                  // 1024
    int orig = (bid & 7) * 128 + (bid >> 3);
    int coh = orig & 1;
    int rowu = orig >> 1;                  // [0,512)
    int y = rowu & 255;
    int b = rowu >> 8;
    int tid = threadIdx.x, lane = tid & 63, wid = tid >> 6;
    int m = lane & 15, grp = lane >> 4;
    int xw = wid * 64;                     // wave's 64-px span
    // ---- phase 1: per-pixel softmax ----
    int x = xw + lane;
    int idx0 = (b << 16) + (y << 8) + x;
    float di = db0[idx0] + db1[idx0];
    float p[9], mx = -1e30f;
#pragma unroll
    for (int k = 0; k < 9; k++) {
        int dy = k / 3 - 1, dx = k % 3 - 1;
        int yy = y + dy, xxn = x + dx;
        bool ok = ((unsigned)yy < 256u) && ((unsigned)xxn < 256u);
        float e = -1e30f;
        if (ok) {
            int nn = (b << 16) + (yy << 8) + xxn;
            float t = sb0[nn] + sb1[nn] + di;
            e = t > 0.f ? t : 0.2f * t;
        }
        p[k] = e;
        mx = fmaxf(mx, e);
    }
    float den = 0.f;
#pragma unroll
    for (int k = 0; k < 9; k++) { p[k] = __expf(p[k] - mx); den += p[k]; }
    float rden = 1.f / (den + 1e-16f);
    unsigned short pb[9];
#pragma unroll
    for (int k = 0; k < 9; k++) pb[k] = f2bf(p[k] * rden);
    unsigned pk0 = (unsigned)pb[0] | ((unsigned)pb[1] << 16);
    unsigned pk1 = (unsigned)pb[2] | ((unsigned)pb[3] << 16);
    unsigned pk2 = (unsigned)pb[4] | ((unsigned)pb[5] << 16);
    unsigned pk3 = (unsigned)pb[6] | ((unsigned)pb[7] << 16);
    unsigned pk4 = (unsigned)pb[8];
    float sAcc[NT2], qAcc[NT2], bb[NT2];
#pragma unroll
    for (int ct = 0; ct < NT2; ct++) {
        sAcc[ct] = 0.f; qAcc[ct] = 0.f;
        bb[ct] = gb[coh * CH + ct * 16 + m];
    }
    // ---- phase 2: 4 tiles ----
#pragma unroll 1
    for (int t = 0; t < 4; t++) {
        int xb = xw + t * 16;
        int src = t * 16 + m;
        unsigned rk0 = __shfl(pk0, src);
        unsigned rk1 = __shfl(pk1, src);
        unsigned rk2 = __shfl(pk2, src);
        unsigned rk3 = __shfl(pk3, src);
        unsigned rk4 = __shfl(pk4, src);
        unsigned short rb[9];
        rb[0] = (unsigned short)rk0; rb[1] = (unsigned short)(rk0 >> 16);
        rb[2] = (unsigned short)rk1; rb[3] = (unsigned short)(rk1 >> 16);
        rb[4] = (unsigned short)rk2; rb[5] = (unsigned short)(rk2 >> 16);
        rb[6] = (unsigned short)rk3; rb[7] = (unsigned short)(rk3 >> 16);
        rb[8] = (unsigned short)rk4;
        union { bf8v v; unsigned short h[8]; } af[3];
#pragma unroll
        for (int dyi = 0; dyi < 3; dyi++)
#pragma unroll
            for (int j = 0; j < 8; j++) {
                int k = grp * 8 + j;
                int d = k - 8 - m;
                af[dyi].h[j] = (d >= -1 && d <= 1) ? rb[dyi * 3 + d + 1] : (unsigned short)0;
            }
        f4v acc[NT2];
        f4v z4 = {0.f, 0.f, 0.f, 0.f};
#pragma unroll
        for (int ct = 0; ct < NT2; ct++) acc[ct] = z4;
        int px0 = xb - 8 + grp * 8;
        px0 = px0 < 0 ? 0 : (px0 > 248 ? 248 : px0);
#pragma unroll
        for (int dyi = 0; dyi < 3; dyi++) {
            int yy = y + dyi - 1;
            if ((unsigned)yy >= 256u) continue;
#pragma unroll
            for (int ct = 0; ct < NT2; ct++) {
                int ch = coh * CH + ct * 16 + m;
                bf8v bv = *(const bf8v*)(hb + (((size_t)(b * CO + ch)) << 16) + (yy << 8) + px0);
                acc[ct] = __builtin_amdgcn_mfma_f32_16x16x32_bf16(af[dyi].v, bv, acc[ct], 0, 0, 0);
            }
        }
        int pxr = xb + grp * 4;
#pragma unroll
        for (int ct = 0; ct < NT2; ct++) {
            int ch = coh * CH + ct * 16 + m;
            f4v a = acc[ct];
            float o0 = fmaxf(a[0] + bb[ct], 0.f);
            float o1 = fmaxf(a[1] + bb[ct], 0.f);
            float o2 = fmaxf(a[2] + bb[ct], 0.f);
            float o3 = fmaxf(a[3] + bb[ct], 0.f);
            us4 pkst = {f2bf(o0), f2bf(o1), f2bf(o2), f2bf(o3)};
            *(us4*)(out + (((size_t)(b * CO + ch)) << 16) + (y << 8) + pxr) = pkst;
            sAcc[ct] += o0 + o1 + o2 + o3;
            qAcc[ct] += o0 * o0 + o1 * o1 + o2 * o2 + o3 * o3;
        }
    }
    // ---- stats ----
#pragma unroll
    for (int ct = 0; ct < NT2; ct++) {
        sAcc[ct] += __shfl_xor(sAcc[ct], 16); sAcc[ct] += __shfl_xor(sAcc[ct], 32);
        qAcc[ct] += __shfl_xor(qAcc[ct], 16); qAcc[ct] += __shfl_xor(qAcc[ct], 32);
    }
    __shared__ float red[2][NT2][16][4];
    if (grp == 0) {
#pragma unroll
        for (int ct = 0; ct < NT2; ct++) {
            red[0][ct][m][wid] = sAcc[ct];
            red[1][ct][m][wid] = qAcc[ct];
        }
    }
    __syncthreads();
    if (tid < CH) {
        int ct = tid >> 4, mm = tid & 15;
        int c = coh * CH + tid;
        float s = red[0][ct][mm][0] + red[0][ct][mm][1] + red[0][ct][mm][2] + red[0][ct][mm][3];
        float qq = red[1][ct][mm][0] + red[1][ct][mm][1] + red[1][ct][mm][2] + red[1][ct][mm][3];
        atomicAdd(&st[c], s);
        atomicAdd(&st[CO + c], qq);
        if (POOL) atomicAdd(&st[2 * CO + b * CO + c], s);
    }
}

// ---------------- ff (bf16 out) + transpose + FUSED channel-weight MLP ----------------
__global__ __launch_bounds__(256) void ff_t(const unsigned short* __restrict__ g64,
                                            const float* __restrict__ raw3,
                                            const float* __restrict__ g3,
                                            const float* __restrict__ b3,
                                            const float* __restrict__ w1,
                                            const float* __restrict__ bb1,
                                            const float* __restrict__ w2,
                                            const float* __restrict__ bb2,
                                            const float* __restrict__ filt,
                                            const float* __restrict__ fbias,
                                            unsigned short* __restrict__ ffout,
                                            unsigned* __restrict__ at1) {
    __shared__ float pooled[2][64];
    __shared__ float hsh[2][16];
    __shared__ float cwsh[2][64];
    __shared__ unsigned t[64 * 33];
    int tid = threadIdx.x;
    if (tid < 128) {
        int b = tid >> 6, c = tid & 63;
        float A, Bv;
        bn_coef(raw3, g3, b3, 64, c, A, Bv);
        float sm = raw3[128 + (b << 6) + c];
        pooled[b][c] = fmaf(sm * (1.f / 65536.f), A, Bv);
    }
    __syncthreads();
    if (tid < 32) {
        int b = tid >> 4, j = tid & 15;
        float acc = bb1[j];
        for (int c2 = 0; c2 < 64; c2++) acc = fmaf(pooled[b][c2], w1[(j << 6) + c2], acc);
        hsh[b][j] = fmaxf(acc, 0.f);
    }
    __syncthreads();
    if (tid < 128) {
        int b = tid >> 6, c = tid & 63;
        float logit = bb2[c];
        for (int j = 0; j < 16; j++) logit = fmaf(hsh[b][j], w2[(c << 4) + j], logit);
        float mm = logit;
#pragma unroll
        for (int off = 32; off; off >>= 1) mm = fmaxf(mm, __shfl_xor(mm, off));
        float e = __expf(logit - mm);
        float ss = e;
#pragma unroll
        for (int off = 32; off; off >>= 1) ss += __shfl_xor(ss, off);
        cwsh[b][c] = e / ss;
    }
    __syncthreads();
    int pxb = blockIdx.x * 64;
    int b = pxb >> 16;
    int nb = pxb & 65535;
#pragma unroll
    for (int k = 0; k < 2; k++) {
        int u = tid + k * 256;
        int q = u & 15;
        int cp = u >> 4;
        int ch0 = cp * 2, ch1 = ch0 + 1;
        float A0, B0, A1, B1;
        bn_coef(raw3, g3, b3, 64, ch0, A0, B0);
        bn_coef(raw3, g3, b3, 64, ch1, A1, B1);
        float s0 = cwsh[b][ch0], s1 = cwsh[b][ch1];
        float fb0 = fbias[ch0], fb1 = fbias[ch1];
        int n = nb + q * 4;
        us4 r0 = *(const us4*)(g64 + ((size_t)(b * 64 + ch0) << 16) + n);
        us4 r1 = *(const us4*)(g64 + ((size_t)(b * 64 + ch1) << 16) + n);
        float4 l0 = *(const float4*)(filt + ((size_t)ch0 << 16) + n);
        float4 l1 = *(const float4*)(filt + ((size_t)ch1 << 16) + n);
        float4 o0, o1;
        o0.x = fmaf(fmaf(bf2f(r0[0]), A0, B0) * s0, l0.x, fb0);
        o0.y = fmaf(fmaf(bf2f(r0[1]), A0, B0) * s0, l0.y, fb0);
        o0.z = fmaf(fmaf(bf2f(r0[2]), A0, B0) * s0, l0.z, fb0);
        o0.w = fmaf(fmaf(bf2f(r0[3]), A0, B0) * s0, l0.w, fb0);
        o1.x = fmaf(fmaf(bf2f(r1[0]), A1, B1) * s1, l1.x, fb1);
        o1.y = fmaf(fmaf(bf2f(r1[1]), A1, B1) * s1, l1.y, fb1);
        o1.z = fmaf(fmaf(bf2f(r1[2]), A1, B1) * s1, l1.z, fb1);
        o1.w = fmaf(fmaf(bf2f(r1[3]), A1, B1) * s1, l1.w, fb1);
        us4 f0 = {f2bf(o0.x), f2bf(o0.y), f2bf(o0.z), f2bf(o0.w)};
        us4 f1 = {f2bf(o1.x), f2bf(o1.y), f2bf(o1.z), f2bf(o1.w)};
        *(us4*)(ffout + ((size_t)(b * 64 + ch0) << 16) + n) = f0;
        *(us4*)(ffout + ((size_t)(b * 64 + ch1) << 16) + n) = f1;
#pragma unroll
        for (int i = 0; i < 4; i++)
            t[(q * 4 + i) * 33 + cp] = (unsigned)f0[i] | ((unsigned)f1[i] << 16);
    }
    __syncthreads();
#pragma unroll
    for (int j = 0; j < 8; j++) {
        int lin = j * 256 + tid;
        int pl = lin >> 5, cp = lin & 31;
        unsigned v = t[pl * 33 + cp];
        int P = pxb + pl;
        size_t byte = ((size_t)P << 7) + ((cp >= 16) ? 64 : 0)
                    + (((cp & 15) * 4) ^ (((P >> 1) & 3) << 4));
        *(unsigned*)((char*)at1 + byte) = v;
    }
}

// ---------------- enh1: 3x3 conv 64->32 via MFMA, relu, bf16 out (swizzled) ----------------
__global__ __launch_bounds__(256) void enh1_mfma(const unsigned short* __restrict__ at1,
                                                 const unsigned short* __restrict__ wb,  // [9][32][64]
                                                 const float* __restrict__ bias,
                                                 unsigned short* __restrict__ at2) {
    int y, b;
    row_swz512(blockIdx.x, y, b);
    int tid = threadIdx.x;
    int lane = tid & 63, wid = tid >> 6;
    __shared__ __align__(16) unsigned short lds_u16[3 * 258 * 32];
    char* ldsb = (char*)lds_u16;
    {
        bf8v z = {0, 0, 0, 0, 0, 0, 0, 0};
        for (int i = tid; i < 3 * 258 * 32 / 8; i += 256) ((bf8v*)lds_u16)[i] = z;
    }
    f4v acc[4][2];
    {
        f4v z4 = {0.f, 0.f, 0.f, 0.f};
#pragma unroll
        for (int m = 0; m < 4; m++) { acc[m][0] = z4; acc[m][1] = z4; }
    }
#pragma unroll 1
    for (int kh = 0; kh < 2; kh++) {
        __syncthreads();
        for (int c = wid; c < 48; c += 4) {
            int r = c >> 4, k = c & 15;
            int yy = y + r - 1;
            if ((unsigned)yy < 256u) {
                const char* src = (const char*)at1
                    + (((size_t)((b << 16) + (yy << 8)) + (k * 16 + (lane >> 2))) << 7)
                    + kh * 64 + (lane & 3) * 16;
                char* dst = ldsb + (r * 258 + 1) * 64 + k * 1024;
                GLL16(src, dst);
            }
        }
        __syncthreads();
        bf8v bw0[9], bw1[9];
#pragma unroll
        for (int pos = 0; pos < 9; pos++) {
            bw0[pos] = *(const bf8v*)(wb + (pos * 32 + (lane & 15)) * 64 + kh * 32 + (lane >> 4) * 8);
            bw1[pos] = *(const bf8v*)(wb + (pos * 32 + 16 + (lane & 15)) * 64 + kh * 32 + (lane >> 4) * 8);
        }
#pragma unroll
        for (int mt = 0; mt < 4; mt++) {
            int xb = (wid * 4 + mt) * 16 + (lane & 15);
#pragma unroll
            for (int ky = 0; ky < 3; ky++) {
#pragma unroll
                for (int kx = 0; kx < 3; kx++) {
                    int x = xb + kx - 1;
                    int s = x + 1;
                    int off = (ky * 258 + s) * 64 + (((lane >> 4) * 16) ^ (((x >> 1) & 3) << 4));
                    bf8v a = *(const bf8v*)(ldsb + off);
                    acc[mt][0] = __builtin_amdgcn_mfma_f32_16x16x32_bf16(a, bw0[ky * 3 + kx], acc[mt][0], 0, 0, 0);
                    acc[mt][1] = __builtin_amdgcn_mfma_f32_16x16x32_bf16(a, bw1[ky * 3 + kx], acc[mt][1], 0, 0, 0);
                }
            }
        }
    }
    float bb[2] = {bias[lane & 15], bias[16 + (lane & 15)]};
#pragma unroll
    for (int mt = 0; mt < 4; mt++) {
#pragma unroll
        for (int nt = 0; nt < 2; nt++) {
            f4v v = acc[mt][nt];
            int co = nt * 16 + (lane & 15);
#pragma unroll
            for (int r = 0; r < 4; r++) {
                int x = (wid * 4 + mt) * 16 + (lane >> 4) * 4 + r;
                float val = fmaxf(v[r] + bb[nt], 0.f);
                size_t byte = (((size_t)((b << 16) + (y << 8) + x)) << 6)
                            + ((co * 2) ^ (((x >> 1) & 3) << 4));
                *(unsigned short*)((char*)at2 + byte) = f2bf(val);
            }
        }
    }
}

// ---------------- enh2: 3x3 conv 32->64 MFMA + bf16 residual + relu -> bf16 ENH + bn4 stats ----------------
__global__ __launch_bounds__(256) void enh2_mfma(const unsigned short* __restrict__ at2,
                                                 const unsigned short* __restrict__ wb,  // [9][64][32]
                                                 const float* __restrict__ bias,
                                                 const unsigned short* __restrict__ ff,
                                                 unsigned short* __restrict__ enh,
                                                 float* __restrict__ st) {
    int y, b;
    row_swz512(blockIdx.x, y, b);
    int tid = threadIdx.x;
    int lane = tid & 63, wid = tid >> 6;
    __shared__ __align__(16) unsigned short lds_u16[3 * 258 * 32];
    char* ldsb = (char*)lds_u16;
    {
        bf8v z = {0, 0, 0, 0, 0, 0, 0, 0};
        for (int i = tid; i < 3 * 258 * 32 / 8; i += 256) ((bf8v*)lds_u16)[i] = z;
    }
    __syncthreads();
    for (int c = wid; c < 48; c += 4) {
        int r = c >> 4, k = c & 15;
        int yy = y + r - 1;
        if ((unsigned)yy < 256u) {
            const char* src = (const char*)at2
                + (((size_t)((b << 16) + (yy << 8))) << 6) + k * 1024 + lane * 16;
            char* dst = ldsb + (r * 258 + 1) * 64 + k * 1024;
            GLL16(src, dst);
        }
    }
    __syncthreads();
    f4v acc[4][4];
    {
        f4v z4 = {0.f, 0.f, 0.f, 0.f};
#pragma unroll
        for (int m = 0; m < 4; m++)
#pragma unroll
            for (int n = 0; n < 4; n++) acc[m][n] = z4;
    }
#pragma unroll
    for (int np = 0; np < 2; np++) {
        bf8v bw0[9], bw1[9];
#pragma unroll
        for (int pos = 0; pos < 9; pos++) {
            bw0[pos] = *(const bf8v*)(wb + (pos * 64 + np * 32 + (lane & 15)) * 32 + (lane >> 4) * 8);
            bw1[pos] = *(const bf8v*)(wb + (pos * 64 + np * 32 + 16 + (lane & 15)) * 32 + (lane >> 4) * 8);
        }
#pragma unroll
        for (int mt = 0; mt < 4; mt++) {
            int xb = (wid * 4 + mt) * 16 + (lane & 15);
#pragma unroll
            for (int ky = 0; ky < 3; ky++) {
#pragma unroll
                for (int kx = 0; kx < 3; kx++) {
                    int x = xb + kx - 1;
                    int s = x + 1;
                    int off = (ky * 258 + s) * 64 + (((lane >> 4) * 16) ^ (((x >> 1) & 3) << 4));
                    bf8v a = *(const bf8v*)(ldsb + off);
                    acc[mt][2 * np]     = __builtin_amdgcn_mfma_f32_16x16x32_bf16(a, bw0[ky * 3 + kx], acc[mt][2 * np], 0, 0, 0);
                    acc[mt][2 * np + 1] = __builtin_amdgcn_mfma_f32_16x16x32_bf16(a, bw1[ky * 3 + kx], acc[mt][2 * np + 1], 0, 0, 0);
                }
            }
        }
    }
    __syncthreads();
    float* red = (float*)lds_u16;  // [64 co][4 wave][2]
#pragma unroll
    for (int nt = 0; nt < 4; nt++) {
        int co = nt * 16 + (lane & 15);
        float bb = bias[co];
        float s = 0.f, q = 0.f;
#pragma unroll
        for (int mt = 0; mt < 4; mt++) {
            int xb4 = (wid * 4 + mt) * 16 + (lane >> 4) * 4;
            size_t idx = ((size_t)(b * 64 + co) << 16) + (y << 8) + xb4;
            us4 rv = *(const us4*)(ff + idx);
            f4v a = acc[mt][nt];
            us4 ro;
            ro[0] = f2bf(fmaxf(a[0] + bb + bf2f(rv[0]), 0.f));
            ro[1] = f2bf(fmaxf(a[1] + bb + bf2f(rv[1]), 0.f));
            ro[2] = f2bf(fmaxf(a[2] + bb + bf2f(rv[2]), 0.f));
            ro[3] = f2bf(fmaxf(a[3] + bb + bf2f(rv[3]), 0.f));
            *(us4*)(enh + idx) = ro;
            float r0 = bf2f(ro[0]), r1 = bf2f(ro[1]), r2 = bf2f(ro[2]), r3 = bf2f(ro[3]);
            s += r0 + r1 + r2 + r3;
            q += r0 * r0 + r1 * r1 + r2 * r2 + r3 * r3;
        }
        s += __shfl_xor(s, 16); s += __shfl_xor(s, 32);
        q += __shfl_xor(q, 16); q += __shfl_xor(q, 32);
        if (lane < 16) {
            red[(co * 4 + wid) * 2 + 0] = s;
            red[(co * 4 + wid) * 2 + 1] = q;
        }
    }
    __syncthreads();
    if (tid < 64) {
        float s = 0.f, q = 0.f;
#pragma unroll
        for (int w = 0; w < 4; w++) {
            s += red[(tid * 4 + w) * 2 + 0];
            q += red[(tid * 4 + w) * 2 + 1];
        }
        atomicAdd(&st[tid], s);
        atomicAdd(&st[64 + tid], q);
    }
}

// ---------------- final BN apply: bf16 ENH -> fp32 d_out ----------------
__global__ void bn_apply4(const us4* __restrict__ enh, float4* __restrict__ io,
                          const float* __restrict__ raw,
                          const float* __restrict__ g, const float* __restrict__ b) {
    int t = blockIdx.x * 256 + threadIdx.x;
    int c = (t >> 14) & 63;
    float A, Bv;
    bn_coef(raw, g, b, 64, c, A, Bv);
    us4 v = enh[t];
    float4 o;
    o.x = fmaf(bf2f(v[0]), A, Bv);
    o.y = fmaf(bf2f(v[1]), A, Bv);
    o.z = fmaf(bf2f(v[2]), A, Bv);
    o.w = fmaf(bf2f(v[3]), A, Bv);
    io[t] = o;
}

extern "C" void kernel_launch(void* const* d_in, const int* in_sizes, int n_in,
                              void* d_out, int out_size, void* d_ws, size_t ws_size,
                              hipStream_t stream) {
    const float* x       = (const float*)d_in[0];
    const float* conv1_w = (const float*)d_in[1];
    const float* conv1_b = (const float*)d_in[2];
    const float* bn1_g   = (const float*)d_in[3];
    const float* bn1_b   = (const float*)d_in[4];
    const float* pos1_w  = (const float*)d_in[5];
    const float* pos1_b  = (const float*)d_in[6];
    const float* gat1_w  = (const float*)d_in[7];
    const float* gat1_as = (const float*)d_in[8];
    const float* gat1_ad = (const float*)d_in[9];
    const float* gat1_b  = (const float*)d_in[10];
    const float* bn2_g   = (const float*)d_in[11];
    const float* bn2_b   = (const float*)d_in[12];
    const float* pos2_w  = (const float*)d_in[13];
    const float* pos2_b  = (const float*)d_in[14];
    const float* gat2_w  = (const float*)d_in[15];
    const float* gat2_as = (const float*)d_in[16];
    const float* gat2_ad = (const float*)d_in[17];
    const float* gat2_b  = (const float*)d_in[18];
    const float* bn3_g   = (const float*)d_in[19];
    const float* bn3_b   = (const float*)d_in[20];
    const float* mlp1_w  = (const float*)d_in[21];
    const float* mlp1_b  = (const float*)d_in[22];
    const float* mlp2_w  = (const float*)d_in[23];
    const float* mlp2_b  = (const float*)d_in[24];
    const float* filt    = (const float*)d_in[25];
    const float* fbias   = (const float*)d_in[26];
    const float* enh1_w  = (const float*)d_in[27];
    const float* enh1_b  = (const float*)d_in[28];
    const float* enh2_w  = (const float*)d_in[29];
    const float* enh2_b  = (const float*)d_in[30];
    const float* bn4_g   = (const float*)d_in[31];
    const float* bn4_b   = (const float*)d_in[32];

    float* ws = (float*)d_ws;
    unsigned short* P0 = (unsigned short*)(ws + OFF_W0);   // A16 / G32 / G64 (bf16)
    unsigned short* HB = (unsigned short*)(ws + OFF_W1);   // H32 / H64 (bf16)
    unsigned short* FFB = (unsigned short*)(ws + OFF_W1);  // ff bf16 (after H dead)
    unsigned* AT1 = (unsigned*)(ws + OFF_W2);
    unsigned short* ENH = (unsigned short*)(ws + OFF_W2);  // enh bf16 (after AT1 dead)
    unsigned short* AT2 = (unsigned short*)(ws + OFF_W3);  // enh phase only
    float* SB0 = ws + OFF_S;
    float* DB0 = ws + OFF_D;
    float* SB1 = ws + OFF_W3;                              // GAT phase only (W3 free)
    float* DB1 = ws + OFF_W3 + 131072;
    float* ST1 = ws + OFF_ST1;
    float* ST2 = ws + OFF_ST2;
    float* ST3 = ws + OFF_ST3;
    float* ST4 = ws + OFF_ST4;
    unsigned short* WB1 = (unsigned short*)(ws + OFF_WB1);
    unsigned short* WB2 = (unsigned short*)(ws + OFF_WB2);
    float* out = (float*)d_out;

    // 0. fused prep: zero stats + repack both enh weights
    prep<<<147, 256, 0, stream>>>(ws + OFF_STAT, enh1_w, WB1, enh2_w, WB2);

    // 1. conv1 5x5 + relu -> A16 bf16 (P0), fused bn1 stats
    conv5x5_all<<<dim3(256, 2), 256, 0, stream>>>(x, conv1_w, conv1_b, P0, ST1);

    // 2. gat1 pre (co-split) -> H32 bf16 (HB), partial S/D
    gat_pre<16, 32><<<dim3(512, 2), 256, 0, stream>>>(P0, ST1, bn1_g, bn1_b, pos1_w, pos1_b,
                                                      gat1_w, gat1_as, gat1_ad, HB,
                                                      SB0, DB0, SB1, DB1);

    // 3. gat1 stencil (MFMA, co-split) + relu -> G32 bf16 (P0), fused bn2 stats
    gat_stencil_mfma<32, false><<<1024, 256, 0, stream>>>(HB, SB0, SB1, DB0, DB1, gat1_b, P0, ST2);

    // 4. gat2 pre (co-split) -> H64 bf16 (HB), partial S/D
    gat_pre<32, 64><<<dim3(512, 2), 256, 0, stream>>>(P0, ST2, bn2_g, bn2_b, pos2_w, pos2_b,
                                                      gat2_w, gat2_as, gat2_ad, HB,
                                                      SB0, DB0, SB1, DB1);

    // 5. gat2 stencil (MFMA, co-split) + relu -> G64 bf16 (P0), fused bn3 stats + pooled
    gat_stencil_mfma<64, true><<<1024, 256, 0, stream>>>(HB, SB0, SB1, DB0, DB1, gat2_b, P0, ST3);

    // 6. ff (with fused MLP+softmax) -> FFB bf16 + AT1 swizzled
    ff_t<<<2048, 256, 0, stream>>>(P0, ST3, bn3_g, bn3_b, mlp1_w, mlp1_b, mlp2_w, mlp2_b,
                                   filt, fbias, FFB, AT1);

    // 7. enh1 MFMA -> AT2
    enh1_mfma<<<512, 256, 0, stream>>>((const unsigned short*)AT1, WB1, enh1_b, AT2);

    // 8. enh2 MFMA + bf16 residual + relu -> ENH bf16, fused bn4 stats
    enh2_mfma<<<512, 256, 0, stream>>>(AT2, WB2, enh2_b, FFB, ENH, ST4);

    // 9. bn4 apply: bf16 ENH -> fp32 d_out
    bn_apply4<<<8192, 256, 0, stream>>>((const us4*)ENH, (float4*)out, ST4, bn4_g, bn4_b);
}